// Round 1
// 401.536 us; speedup vs baseline: 1.0234x; 1.0234x over previous
//
#include <hip/hip_runtime.h>
#include <math.h>

#define N_NODES 100000
#define N_EDGES 1600000
#define DIM     128
#define NCLS    40
#define NBUCK   196      // ceil(100000/512) buckets of 512 nodes
#define P1_CH   4096     // edges per phase-1 block
#define P1_GRID 391      // ceil(1600000/4096)

typedef _Float16 f16x8 __attribute__((ext_vector_type(8)));
typedef _Float16 f16x2 __attribute__((ext_vector_type(2)));
typedef float    f32x4 __attribute__((ext_vector_type(4)));

__device__ inline unsigned short f16bits(float f) {
    union { _Float16 h; unsigned short u; } cv;
    cv.h = (_Float16)f;
    return cv.u;
}
__device__ inline f16x2 as_h2(unsigned u) {
    union { unsigned u; f16x2 h; } cv;
    cv.u = u;
    return cv.h;
}
__device__ inline unsigned as_u(f16x2 h) {
    union { f16x2 h; unsigned u; } cv;
    cv.h = h;
    return cv.u;
}
__device__ inline unsigned pack_h2(float lo, float hi) {
    f16x2 h;
    h.x = (_Float16)lo;
    h.y = (_Float16)hi;
    return as_u(h);
}
__device__ inline int wave_incl_scan(int v, int lane) {
#pragma unroll
    for (int off = 1; off < 64; off <<= 1) {
        int x = __shfl_up(v, off, 64);
        if (lane >= off) v += x;
    }
    return v;
}

// ---------------------------------------------------------------- setup: W swizzles + bucket histogram (bcnt pre-zeroed)
__global__ __launch_bounds__(256) void setup_misc(const float* __restrict__ W0,
                                                  const float* __restrict__ W1,
                                                  const float* __restrict__ W2,
                                                  const float* __restrict__ Wc,
                                                  const int* __restrict__ ei,
                                                  unsigned short* __restrict__ Wsw0,
                                                  unsigned short* __restrict__ Wsw1,
                                                  unsigned short* __restrict__ Wsw2,
                                                  unsigned short* __restrict__ Wcsw,
                                                  int* __restrict__ bcnt) {
    int blk = blockIdx.x;
    if (blk < 192) {
        const float* W = (blk < 64) ? W0 : (blk < 128) ? W1 : W2;
        unsigned short* Wsw = (blk < 64) ? Wsw0 : (blk < 128) ? Wsw1 : Wsw2;
        int o = (blk & 63) * 256 + threadIdx.x;  // 0..16383
        int f = o >> 9;
        int l = (o >> 3) & 63;
        int j = o & 7;
        int n = f >> 2;
        int s = f & 3;
        int k = s * 32 + (l >> 4) * 8 + j;
        int c = (l & 15) * 8 + n;
        Wsw[o] = f16bits(W[k * DIM + c]);
    } else if (blk < 216) {
        int o = (blk - 192) * 256 + threadIdx.x; // 0..6143
        int f = o >> 9;
        int l = (o >> 3) & 63;
        int j = o & 7;
        int n = f >> 2;
        int s = f & 3;
        int k = s * 32 + (l >> 4) * 8 + j;
        int c = (l & 15) * 3 + n;
        Wcsw[o] = (c < NCLS) ? f16bits(Wc[k * NCLS + c]) : (unsigned short)0;
    } else {
        __shared__ int h[256];
        const int t  = threadIdx.x;
        const int e0 = (blk - 216) * P1_CH;
        const int cnt = min(P1_CH, N_EDGES - e0);
        h[t] = 0;
        __syncthreads();
        for (int i = t; i < cnt; i += 256)
            atomicAdd(&h[ei[N_EDGES + e0 + i] >> 9], 1);
        __syncthreads();
        if (h[t]) atomicAdd(&bcnt[t], h[t]);
    }
}

// ---------------------------------------------------------------- bucket scan (1 block): bbase (exclusive), bcur = bbase
__global__ __launch_bounds__(256) void bscan(const int* __restrict__ bcnt,
                                             int* __restrict__ bbase,
                                             int* __restrict__ bcur) {
    __shared__ int wtot[4];
    int t = threadIdx.x;
    int lane = t & 63, wv = t >> 6;
    int v = (t < NBUCK) ? bcnt[t] : 0;
    int incl = wave_incl_scan(v, lane);
    if (lane == 63) wtot[wv] = incl;
    __syncthreads();
    int prefix = 0;
    for (int i = 0; i < wv; ++i) prefix += wtot[i];
    incl += prefix;
    int excl = incl - v;
    if (t < NBUCK) {
        bbase[t] = excl;
        bcur[t]  = excl;
    }
    if (t == 0) bbase[NBUCK] = N_EDGES;
}

// ---------------------------------------------------------------- phase 1: bucket edges by dst>>9 into packed tmp
// tmp entry = (s<<9) | (d & 511)
__global__ __launch_bounds__(256) void bucket_p1(const int* __restrict__ ei,
                                                 int* __restrict__ bcur,
                                                 unsigned* __restrict__ tmp) {
    __shared__ int  hist[256];
    __shared__ int  lscan[256];
    __shared__ int  rank[256];
    __shared__ int  gbase[256];
    __shared__ int  wtot[4];
    __shared__ int2 stage[P1_CH];      // 32 KB
    const int t  = threadIdx.x;
    const int lane = t & 63, wv = t >> 6;
    const int e0 = blockIdx.x * P1_CH;
    const int cnt = min(P1_CH, N_EDGES - e0);

    hist[t] = 0;
    __syncthreads();

    int2 ed[16];
#pragma unroll
    for (int i = 0; i < 16; ++i) {
        int idx = t + i * 256;
        if (idx < cnt) {
            int s = ei[e0 + idx];
            int d = ei[N_EDGES + e0 + idx];
            ed[i] = make_int2(s, d);
            atomicAdd(&hist[d >> 9], 1);
        }
    }
    __syncthreads();

    int hv = hist[t];
    int incl = wave_incl_scan(hv, lane);
    if (lane == 63) wtot[wv] = incl;
    __syncthreads();
    int prefix = 0;
    for (int i = 0; i < wv; ++i) prefix += wtot[i];
    incl += prefix;
    int excl = incl - hv;
    lscan[t] = excl;
    rank[t]  = excl;
    if (hv > 0) gbase[t] = atomicAdd(&bcur[t], hv);
    __syncthreads();

#pragma unroll
    for (int i = 0; i < 16; ++i) {
        int idx = t + i * 256;
        if (idx < cnt) {
            int b = ed[i].y >> 9;
            int p = atomicAdd(&rank[b], 1);
            stage[p] = ed[i];
        }
    }
    __syncthreads();

    for (int p = t; p < cnt; p += 256) {
        int2 v = stage[p];
        int b = v.y >> 9;
        tmp[gbase[b] + (p - lscan[b])] = ((unsigned)v.x << 9) | ((unsigned)v.y & 511u);
    }
}

// ---------------------------------------------------------------- phase 2 (fused): counts -> rowptr+dinv, then scatter rec=src<<8
__global__ __launch_bounds__(256) void bucket_p2(const unsigned* __restrict__ tmp,
                                                 const int* __restrict__ bbase,
                                                 int* __restrict__ rowptr,
                                                 float* __restrict__ dinv,
                                                 unsigned* __restrict__ rec) {
    __shared__ int cnt[512];
    __shared__ int cur[512];
    __shared__ int wtot[4];
    const int t  = threadIdx.x;
    const int lane = t & 63, wv = t >> 6;
    const int b  = blockIdx.x;
    const int d0 = b << 9;
    const int dend = min(d0 + 512, N_NODES);
    const int nn = dend - d0;

    cnt[t] = 0;
    cnt[t + 256] = 0;
    __syncthreads();

    const int beg = bbase[b];
    const int end = bbase[b + 1];
    for (int idx = beg + t; idx < end; idx += 256)
        atomicAdd(&cnt[tmp[idx] & 511u], 1);
    __syncthreads();

    int c0 = cnt[2 * t];
    int c1 = cnt[2 * t + 1];
    int pv = c0 + c1;
    int incl = wave_incl_scan(pv, lane);
    if (lane == 63) wtot[wv] = incl;
    __syncthreads();
    int prefix = 0;
    for (int i = 0; i < wv; ++i) prefix += wtot[i];
    incl += prefix;
    int excl = incl - pv;
    int base0 = beg + excl;
    int base1 = base0 + c0;
    cur[2 * t]     = base0;
    cur[2 * t + 1] = base1;
    if (2 * t < nn) {
        rowptr[d0 + 2 * t] = base0;
        dinv[d0 + 2 * t]   = rsqrtf((float)c0 + 1.0f);
    }
    if (2 * t + 1 < nn) {
        rowptr[d0 + 2 * t + 1] = base1;
        dinv[d0 + 2 * t + 1]   = rsqrtf((float)c1 + 1.0f);
    }
    if (b == NBUCK - 1 && t == 0) rowptr[N_NODES] = N_EDGES;
    __syncthreads();

    for (int idx = beg + t; idx < end; idx += 256) {
        unsigned u = tmp[idx];
        int pos = atomicAdd(&cur[u & 511u], 1);
        rec[pos] = (u >> 9) << 8;       // src byte-offset
    }
}

// ---------------------------------------------------------------- MFMA GEMM, fp32 input (layer 0): out rows scaled by dinv[row]
__global__ __launch_bounds__(256) void gemm_mfma_f(const float* __restrict__ X,
                                                   const unsigned short* __restrict__ Wsw,
                                                   const float* __restrict__ dinv,
                                                   unsigned short* __restrict__ H) {
    __shared__ unsigned short wlds[32 * 512];   // 32 KB
    const int tid   = threadIdx.x;
    const int lane  = tid & 63;
    const int wave  = tid >> 6;
    const int row0w = blockIdx.x * 64 + wave * 16;
    const int m = lane & 15;
    const int q = lane >> 4;

    {
        const uint4* srcp = (const uint4*)Wsw;
        uint4*       dstp = (uint4*)wlds;
#pragma unroll
        for (int i = 0; i < 8; ++i) dstp[tid + i * 256] = srcp[tid + i * 256];
    }
    __syncthreads();

    int r = row0w + m;
    if (r >= N_NODES) r = N_NODES - 1;
    const float* xp = X + (size_t)r * DIM + q * 8;
    f16x8 af[4];
#pragma unroll
    for (int s = 0; s < 4; ++s) {
        float4 x0 = *(const float4*)(xp + s * 32);
        float4 x1 = *(const float4*)(xp + s * 32 + 4);
        f16x8 v;
        v[0] = (_Float16)x0.x; v[1] = (_Float16)x0.y;
        v[2] = (_Float16)x0.z; v[3] = (_Float16)x0.w;
        v[4] = (_Float16)x1.x; v[5] = (_Float16)x1.y;
        v[6] = (_Float16)x1.z; v[7] = (_Float16)x1.w;
        af[s] = v;
    }

    f32x4 acc[8];
    f32x4 z = {0.f, 0.f, 0.f, 0.f};
#pragma unroll
    for (int n = 0; n < 8; ++n) acc[n] = z;

    const unsigned short* wl = wlds + lane * 8;
#pragma unroll
    for (int s = 0; s < 4; ++s)
#pragma unroll
        for (int n = 0; n < 8; ++n) {
            f16x8 wf = *(const f16x8*)(wl + ((n * 4 + s) << 9));
            acc[n] = __builtin_amdgcn_mfma_f32_16x16x32_f16(af[s], wf, acc[n], 0, 0, 0);
        }

#pragma unroll
    for (int j = 0; j < 4; ++j) {
        int row = row0w + q * 4 + j;
        if (row < N_NODES) {
            float dv = dinv[row];
            uint4 o;
            o.x = pack_h2(acc[0][j] * dv, acc[1][j] * dv);
            o.y = pack_h2(acc[2][j] * dv, acc[3][j] * dv);
            o.z = pack_h2(acc[4][j] * dv, acc[5][j] * dv);
            o.w = pack_h2(acc[6][j] * dv, acc[7][j] * dv);
            *(uint4*)(H + (size_t)row * DIM + m * 8) = o;
        } else {
            uint4 zz = make_uint4(0u, 0u, 0u, 0u);   // zero pad rows (gather sentinel)
            *(uint4*)(H + (size_t)row * DIM + m * 8) = zz;
        }
    }
}

// ---------------------------------------------------------------- MFMA GEMM, f16 input (layers 1,2): out rows scaled by dinv[row]
__global__ __launch_bounds__(256) void gemm_mfma_h(const unsigned short* __restrict__ Xh,
                                                   const unsigned short* __restrict__ Wsw,
                                                   const float* __restrict__ dinv,
                                                   unsigned short* __restrict__ H) {
    __shared__ unsigned short wlds[32 * 512];   // 32 KB
    const int tid   = threadIdx.x;
    const int lane  = tid & 63;
    const int wave  = tid >> 6;
    const int row0w = blockIdx.x * 64 + wave * 16;
    const int m = lane & 15;
    const int q = lane >> 4;

    {
        const uint4* srcp = (const uint4*)Wsw;
        uint4*       dstp = (uint4*)wlds;
#pragma unroll
        for (int i = 0; i < 8; ++i) dstp[tid + i * 256] = srcp[tid + i * 256];
    }
    __syncthreads();

    int r = row0w + m;
    if (r >= N_NODES) r = N_NODES - 1;
    const unsigned short* xp = Xh + (size_t)r * DIM + q * 8;
    f16x8 af[4];
#pragma unroll
    for (int s = 0; s < 4; ++s) af[s] = *(const f16x8*)(xp + s * 32);

    f32x4 acc[8];
    f32x4 z = {0.f, 0.f, 0.f, 0.f};
#pragma unroll
    for (int n = 0; n < 8; ++n) acc[n] = z;

    const unsigned short* wl = wlds + lane * 8;
#pragma unroll
    for (int s = 0; s < 4; ++s)
#pragma unroll
        for (int n = 0; n < 8; ++n) {
            f16x8 wf = *(const f16x8*)(wl + ((n * 4 + s) << 9));
            acc[n] = __builtin_amdgcn_mfma_f32_16x16x32_f16(af[s], wf, acc[n], 0, 0, 0);
        }

#pragma unroll
    for (int j = 0; j < 4; ++j) {
        int row = row0w + q * 4 + j;
        if (row < N_NODES) {
            float dv = dinv[row];
            uint4 o;
            o.x = pack_h2(acc[0][j] * dv, acc[1][j] * dv);
            o.y = pack_h2(acc[2][j] * dv, acc[3][j] * dv);
            o.z = pack_h2(acc[4][j] * dv, acc[5][j] * dv);
            o.w = pack_h2(acc[6][j] * dv, acc[7][j] * dv);
            *(uint4*)(H + (size_t)row * DIM + m * 8) = o;
        } else {
            uint4 zz = make_uint4(0u, 0u, 0u, 0u);
            *(uint4*)(H + (size_t)row * DIM + m * 8) = zz;
        }
    }
}

// ---------------------------------------------------------------- fused gather-aggregate + LN + ELU (+ residual), f16
// v2: QUARTER-WAVE PER NODE. 16 lanes own one node; each lane owns bytes
// l16*16..+15 of the 256B row, so every lane sees every edge -> no cross-lane
// aggregation reduce. 8 gathers in flight per group (32/wave) for latency
// hiding; 4 accumulator banks keep the f16 chain depth equal to v1.
__global__ __launch_bounds__(256) void agg_ln(const unsigned short* __restrict__ Hh,
                                              const unsigned short* __restrict__ xin,
                                              const float* __restrict__ dinv,
                                              const float* __restrict__ bias,
                                              const float* __restrict__ g,
                                              const float* __restrict__ be,
                                              const int* __restrict__ rowptr,
                                              const unsigned* __restrict__ rec,
                                              unsigned short* __restrict__ outb) {
    const int tid  = threadIdx.x;
    const int lane = tid & 63;
    const int l16  = tid & 15;
    const int gb   = lane & 48;                  // group base lane within wave
    const int node = blockIdx.x * 16 + (tid >> 4);
    const int beg  = rowptr[node];
    const int end  = rowptr[node + 1];
    const char* Hb8 = (const char*)Hh;
    const unsigned laneoff = (unsigned)l16 * 16;       // byte offset within row
    const unsigned sentin  = (unsigned)N_NODES << 8;   // zero row

    f16x2 accA[4], accB[4], accC[4], accD[4];
    f16x2 hz = {(_Float16)0.f, (_Float16)0.f};
#pragma unroll
    for (int k = 0; k < 4; ++k) { accA[k] = hz; accB[k] = hz; accC[k] = hz; accD[k] = hz; }

    for (int e0 = beg; e0 < end; e0 += 16) {
        int cnt = min(end - e0, 16);
        unsigned sv = (l16 < cnt) ? rec[e0 + l16] : sentin;
        int cntR = (cnt + 7) & ~7;
        for (int j = 0; j < cntR; j += 8) {
            unsigned o0 = (unsigned)__shfl((int)sv, gb + j + 0, 64) + laneoff;
            unsigned o1 = (unsigned)__shfl((int)sv, gb + j + 1, 64) + laneoff;
            unsigned o2 = (unsigned)__shfl((int)sv, gb + j + 2, 64) + laneoff;
            unsigned o3 = (unsigned)__shfl((int)sv, gb + j + 3, 64) + laneoff;
            unsigned o4 = (unsigned)__shfl((int)sv, gb + j + 4, 64) + laneoff;
            unsigned o5 = (unsigned)__shfl((int)sv, gb + j + 5, 64) + laneoff;
            unsigned o6 = (unsigned)__shfl((int)sv, gb + j + 6, 64) + laneoff;
            unsigned o7 = (unsigned)__shfl((int)sv, gb + j + 7, 64) + laneoff;
            uint4 u0 = *(const uint4*)(Hb8 + o0);
            uint4 u1 = *(const uint4*)(Hb8 + o1);
            uint4 u2 = *(const uint4*)(Hb8 + o2);
            uint4 u3 = *(const uint4*)(Hb8 + o3);
            uint4 u4 = *(const uint4*)(Hb8 + o4);
            uint4 u5 = *(const uint4*)(Hb8 + o5);
            uint4 u6 = *(const uint4*)(Hb8 + o6);
            uint4 u7 = *(const uint4*)(Hb8 + o7);
            accA[0] += as_h2(u0.x); accA[1] += as_h2(u0.y); accA[2] += as_h2(u0.z); accA[3] += as_h2(u0.w);
            accB[0] += as_h2(u1.x); accB[1] += as_h2(u1.y); accB[2] += as_h2(u1.z); accB[3] += as_h2(u1.w);
            accC[0] += as_h2(u2.x); accC[1] += as_h2(u2.y); accC[2] += as_h2(u2.z); accC[3] += as_h2(u2.w);
            accD[0] += as_h2(u3.x); accD[1] += as_h2(u3.y); accD[2] += as_h2(u3.z); accD[3] += as_h2(u3.w);
            accA[0] += as_h2(u4.x); accA[1] += as_h2(u4.y); accA[2] += as_h2(u4.z); accA[3] += as_h2(u4.w);
            accB[0] += as_h2(u5.x); accB[1] += as_h2(u5.y); accB[2] += as_h2(u5.z); accB[3] += as_h2(u5.w);
            accC[0] += as_h2(u6.x); accC[1] += as_h2(u6.y); accC[2] += as_h2(u6.z); accC[3] += as_h2(u6.w);
            accD[0] += as_h2(u7.x); accD[1] += as_h2(u7.y); accD[2] += as_h2(u7.z); accD[3] += as_h2(u7.w);
        }
    }

#pragma unroll
    for (int k = 0; k < 4; ++k) accA[k] = (accA[k] + accB[k]) + (accC[k] + accD[k]);

    const float dv = dinv[node];
    const unsigned nodeoff = ((unsigned)node << 8) + laneoff;
    uint4 hv = *(const uint4*)(Hb8 + nodeoff);       // h'[node] (pre-scaled)
    const int c0 = l16 * 8;
    float4 bb0 = *(const float4*)(bias + c0);
    float4 bb1 = *(const float4*)(bias + c0 + 4);
    f16x2 h0 = as_h2(hv.x), h1 = as_h2(hv.y), h2 = as_h2(hv.z), h3 = as_h2(hv.w);

    float a[8];
    a[0] = ((float)accA[0].x + (float)h0.x) * dv + bb0.x;
    a[1] = ((float)accA[0].y + (float)h0.y) * dv + bb0.y;
    a[2] = ((float)accA[1].x + (float)h1.x) * dv + bb0.z;
    a[3] = ((float)accA[1].y + (float)h1.y) * dv + bb0.w;
    a[4] = ((float)accA[2].x + (float)h2.x) * dv + bb1.x;
    a[5] = ((float)accA[2].y + (float)h2.y) * dv + bb1.y;
    a[6] = ((float)accA[3].x + (float)h3.x) * dv + bb1.z;
    a[7] = ((float)accA[3].y + (float)h3.y) * dv + bb1.w;

    float s1 = 0.f, s2 = 0.f;
#pragma unroll
    for (int i = 0; i < 8; ++i) { s1 += a[i]; s2 += a[i] * a[i]; }
#pragma unroll
    for (int mk = 1; mk <= 8; mk <<= 1) {
        s1 += __shfl_xor(s1, mk, 64);
        s2 += __shfl_xor(s2, mk, 64);
    }
    float mean = s1 * (1.0f / 128.0f);
    float var  = s2 * (1.0f / 128.0f) - mean * mean;
    float rr   = rsqrtf(var + 1e-5f);

    float4 gg0 = *(const float4*)(g + c0);
    float4 gg1 = *(const float4*)(g + c0 + 4);
    float4 ee0 = *(const float4*)(be + c0);
    float4 ee1 = *(const float4*)(be + c0 + 4);

    float r[8];
    r[0] = (a[0] - mean) * rr * gg0.x + ee0.x;
    r[1] = (a[1] - mean) * rr * gg0.y + ee0.y;
    r[2] = (a[2] - mean) * rr * gg0.z + ee0.z;
    r[3] = (a[3] - mean) * rr * gg0.w + ee0.w;
    r[4] = (a[4] - mean) * rr * gg1.x + ee1.x;
    r[5] = (a[5] - mean) * rr * gg1.y + ee1.y;
    r[6] = (a[6] - mean) * rr * gg1.z + ee1.z;
    r[7] = (a[7] - mean) * rr * gg1.w + ee1.w;
#pragma unroll
    for (int i = 0; i < 8; ++i) r[i] = r[i] > 0.0f ? r[i] : expm1f(r[i]);

    if (xin) {
        uint4 xv = *(const uint4*)((const char*)xin + nodeoff);
        f16x2 x0 = as_h2(xv.x), x1 = as_h2(xv.y), x2 = as_h2(xv.z), x3 = as_h2(xv.w);
        r[0] += (float)x0.x; r[1] += (float)x0.y;
        r[2] += (float)x1.x; r[3] += (float)x1.y;
        r[4] += (float)x2.x; r[5] += (float)x2.y;
        r[6] += (float)x3.x; r[7] += (float)x3.y;
    }

    uint4 o;
    o.x = pack_h2(r[0], r[1]);
    o.y = pack_h2(r[2], r[3]);
    o.z = pack_h2(r[4], r[5]);
    o.w = pack_h2(r[6], r[7]);
    *(uint4*)((char*)outb + nodeoff) = o;
}

// ---------------------------------------------------------------- MFMA classifier, f16 input: 32 rows/wave, Wc via LDS
__global__ __launch_bounds__(256) void classifier_mfma(const unsigned short* __restrict__ Xh,
                                                       const unsigned short* __restrict__ Wcsw,
                                                       const float* __restrict__ bc,
                                                       float* __restrict__ out) {
    __shared__ unsigned short wlds[12 * 512];   // 12 KB
    const int tid   = threadIdx.x;
    const int lane  = tid & 63;
    const int wave  = tid >> 6;
    const int row0w = blockIdx.x * 128 + wave * 32;
    const int m = lane & 15;
    const int q = lane >> 4;

    {
        const uint4* srcp = (const uint4*)Wcsw;
        uint4*       dstp = (uint4*)wlds;
#pragma unroll
        for (int i = 0; i < 3; ++i) dstp[tid + i * 256] = srcp[tid + i * 256];
    }
    __syncthreads();

    f16x8 wf[12];
#pragma unroll
    for (int f = 0; f < 12; ++f)
        wf[f] = *(const f16x8*)(wlds + (f << 9) + lane * 8);

    f16x8 af[2][4];
#pragma unroll
    for (int ggr = 0; ggr < 2; ++ggr) {
        int r = row0w + ggr * 16 + m;
        if (r >= N_NODES) r = N_NODES - 1;
        const unsigned short* xp = Xh + (size_t)r * DIM + q * 8;
#pragma unroll
        for (int s = 0; s < 4; ++s) af[ggr][s] = *(const f16x8*)(xp + s * 32);
    }

    f32x4 acc[2][3];
    f32x4 z = {0.f, 0.f, 0.f, 0.f};
#pragma unroll
    for (int ggr = 0; ggr < 2; ++ggr)
#pragma unroll
        for (int n = 0; n < 3; ++n) acc[ggr][n] = z;

#pragma unroll
    for (int s = 0; s < 4; ++s)
#pragma unroll
        for (int n = 0; n < 3; ++n) {
            acc[0][n] = __builtin_amdgcn_mfma_f32_16x16x32_f16(af[0][s], wf[n * 4 + s], acc[0][n], 0, 0, 0);
            acc[1][n] = __builtin_amdgcn_mfma_f32_16x16x32_f16(af[1][s], wf[n * 4 + s], acc[1][n], 0, 0, 0);
        }

    float bcv[3];
#pragma unroll
    for (int n = 0; n < 3; ++n) {
        int c = 3 * m + n;
        bcv[n] = (c < NCLS) ? bc[c] : 0.f;
    }

#pragma unroll
    for (int ggr = 0; ggr < 2; ++ggr)
#pragma unroll
        for (int j = 0; j < 4; ++j) {
            int row = row0w + ggr * 16 + q * 4 + j;
            if (row < N_NODES) {
#pragma unroll
                for (int n = 0; n < 3; ++n) {
                    int c = 3 * m + n;
                    if (c < NCLS)
                        out[(size_t)row * NCLS + c] = acc[ggr][n][j] + bcv[n];
                }
            }
        }
}

// ---------------------------------------------------------------- launch
extern "C" void kernel_launch(void* const* d_in, const int* in_sizes, int n_in,
                              void* d_out, int out_size, void* d_ws, size_t ws_size,
                              hipStream_t stream) {
    const float* x  = (const float*)d_in[0];
    const int*   ei = (const int*)d_in[1];
    const float* W[3]  = {(const float*)d_in[2], (const float*)d_in[6], (const float*)d_in[10]};
    const float* b[3]  = {(const float*)d_in[3], (const float*)d_in[7], (const float*)d_in[11]};
    const float* g[3]  = {(const float*)d_in[4], (const float*)d_in[8], (const float*)d_in[12]};
    const float* be[3] = {(const float*)d_in[5], (const float*)d_in[9], (const float*)d_in[13]};
    const float* Wc = (const float*)d_in[14];
    const float* bc = (const float*)d_in[15];
    float* out = (float*)d_out;

    char* ws = (char*)d_ws;
    const size_t NP = 400128;  // padded (N+1)*4 bytes
    float* dinv   = (float*)(ws);
    int*   rowptr = (int*)  (ws + NP);
    int*   bcnt   = (int*)  (ws + 2 * NP);
    int*   bbase  = (int*)  (ws + 2 * NP + 1024);
    int*   bcur   = (int*)  (ws + 2 * NP + 2048);
    unsigned* rec = (unsigned*)(ws + 2 * NP + 4096);
    unsigned short* Hh = (unsigned short*)(ws + 2 * NP + 4096 + (size_t)N_EDGES * 8);
    unsigned short* Ah = Hh + (size_t)(N_NODES + 64) * DIM;   // Hh has zero-pad rows
    unsigned short* Ch = Ah + (size_t)N_NODES * DIM;
    unsigned short* Wsw0 = Ch + (size_t)N_NODES * DIM;
    unsigned short* Wsw1 = Wsw0 + DIM * DIM;
    unsigned short* Wsw2 = Wsw1 + DIM * DIM;
    unsigned short* Wcsw = Wsw2 + DIM * DIM;   // 12*512 shorts
    unsigned* tmp = (unsigned*)Ch;             // aliases Ch; dead before layer 0 writes Ch

    // ---- setup: zero bcnt (memset) + swizzles + bucket histogram (1 dispatch) ----
    hipMemsetAsync(bcnt, 0, 1024, stream);
    setup_misc<<<216 + P1_GRID, 256, 0, stream>>>(W[0], W[1], W[2], Wc, ei,
                                                  Wsw0, Wsw1, Wsw2, Wcsw, bcnt);

    // ---- CSR build (bucketed, packed tmp, fused phase 2) ----
    bscan<<<1, 256, 0, stream>>>(bcnt, bbase, bcur);
    bucket_p1<<<P1_GRID, 256, 0, stream>>>(ei, bcur, tmp);
    bucket_p2<<<NBUCK, 256, 0, stream>>>(tmp, bbase, rowptr, dinv, rec);

    const int gemm_grid = (N_NODES + 63) / 64;    // 1563 (covers pad rows to 100032)
    const int cls_grid  = (N_NODES + 127) / 128;  // 782
    const int agg_grid  = N_NODES / 16;           // 6250 (16 nodes/block, quarter-wave each)

    // layer 0: x fp32 -> Hh (scaled); agg -> Ch
    gemm_mfma_f<<<gemm_grid, 256, 0, stream>>>(x, Wsw0, dinv, Hh);
    agg_ln<<<agg_grid, 256, 0, stream>>>(Hh, nullptr, dinv, b[0], g[0], be[0], rowptr, rec, Ch);

    // layer 1: Ch -> Hh (scaled); agg (+resid Ch) -> Ah
    gemm_mfma_h<<<gemm_grid, 256, 0, stream>>>(Ch, Wsw1, dinv, Hh);
    agg_ln<<<agg_grid, 256, 0, stream>>>(Hh, Ch, dinv, b[1], g[1], be[1], rowptr, rec, Ah);

    // layer 2: Ah -> Hh (scaled); agg (+resid Ah) -> Ch
    gemm_mfma_h<<<gemm_grid, 256, 0, stream>>>(Ah, Wsw2, dinv, Hh);
    agg_ln<<<agg_grid, 256, 0, stream>>>(Hh, Ah, dinv, b[2], g[2], be[2], rowptr, rec, Ch);

    classifier_mfma<<<cls_grid, 256, 0, stream>>>(Ch, Wcsw, bc, out);
}

// Round 2
// 389.401 us; speedup vs baseline: 1.0553x; 1.0312x over previous
//
#include <hip/hip_runtime.h>
#include <math.h>

#define N_NODES 100000
#define N_EDGES 1600000
#define DIM     128
#define NCLS    40
#define NBUCK   196      // ceil(100000/512) buckets of 512 nodes
#define P1_CH   4096     // edges per phase-1 block
#define P1_GRID 391      // ceil(1600000/4096)

typedef _Float16 f16x8 __attribute__((ext_vector_type(8)));
typedef _Float16 f16x2 __attribute__((ext_vector_type(2)));
typedef float    f32x4 __attribute__((ext_vector_type(4)));

__device__ inline unsigned short f16bits(float f) {
    union { _Float16 h; unsigned short u; } cv;
    cv.h = (_Float16)f;
    return cv.u;
}
__device__ inline f16x2 as_h2(unsigned u) {
    union { unsigned u; f16x2 h; } cv;
    cv.u = u;
    return cv.h;
}
__device__ inline unsigned as_u(f16x2 h) {
    union { f16x2 h; unsigned u; } cv;
    cv.h = h;
    return cv.u;
}
__device__ inline unsigned pack_h2(float lo, float hi) {
    f16x2 h;
    h.x = (_Float16)lo;
    h.y = (_Float16)hi;
    return as_u(h);
}
__device__ inline int wave_incl_scan(int v, int lane) {
#pragma unroll
    for (int off = 1; off < 64; off <<= 1) {
        int x = __shfl_up(v, off, 64);
        if (lane >= off) v += x;
    }
    return v;
}

// ---------------------------------------------------------------- setup: W swizzles + bucket histogram (bcnt pre-zeroed)
__global__ __launch_bounds__(256) void setup_misc(const float* __restrict__ W0,
                                                  const float* __restrict__ W1,
                                                  const float* __restrict__ W2,
                                                  const float* __restrict__ Wc,
                                                  const int* __restrict__ ei,
                                                  unsigned short* __restrict__ Wsw0,
                                                  unsigned short* __restrict__ Wsw1,
                                                  unsigned short* __restrict__ Wsw2,
                                                  unsigned short* __restrict__ Wcsw,
                                                  int* __restrict__ bcnt) {
    int blk = blockIdx.x;
    if (blk < 192) {
        const float* W = (blk < 64) ? W0 : (blk < 128) ? W1 : W2;
        unsigned short* Wsw = (blk < 64) ? Wsw0 : (blk < 128) ? Wsw1 : Wsw2;
        int o = (blk & 63) * 256 + threadIdx.x;  // 0..16383
        int f = o >> 9;
        int l = (o >> 3) & 63;
        int j = o & 7;
        int n = f >> 2;
        int s = f & 3;
        int k = s * 32 + (l >> 4) * 8 + j;
        int c = (l & 15) * 8 + n;
        Wsw[o] = f16bits(W[k * DIM + c]);
    } else if (blk < 216) {
        int o = (blk - 192) * 256 + threadIdx.x; // 0..6143
        int f = o >> 9;
        int l = (o >> 3) & 63;
        int j = o & 7;
        int n = f >> 2;
        int s = f & 3;
        int k = s * 32 + (l >> 4) * 8 + j;
        int c = (l & 15) * 3 + n;
        Wcsw[o] = (c < NCLS) ? f16bits(Wc[k * NCLS + c]) : (unsigned short)0;
    } else {
        __shared__ int h[256];
        const int t  = threadIdx.x;
        const int e0 = (blk - 216) * P1_CH;
        const int cnt = min(P1_CH, N_EDGES - e0);
        h[t] = 0;
        __syncthreads();
        for (int i = t; i < cnt; i += 256)
            atomicAdd(&h[ei[N_EDGES + e0 + i] >> 9], 1);
        __syncthreads();
        if (h[t]) atomicAdd(&bcnt[t], h[t]);
    }
}

// ---------------------------------------------------------------- phase 1: bucket edges by dst>>9 into packed tmp
// Inline redundant scan of bcnt (replaces bscan dispatch); global alloc via boff atomics.
// tmp entry = (s<<9) | (d & 511)
__global__ __launch_bounds__(256) void bucket_p1(const int* __restrict__ ei,
                                                 const int* __restrict__ bcnt,
                                                 int* __restrict__ boff,
                                                 unsigned* __restrict__ tmp) {
    __shared__ int  hist[256];
    __shared__ int  lscan[256];
    __shared__ int  rank[256];
    __shared__ int  gbase[256];
    __shared__ int  wtotA[4];
    __shared__ int  wtotB[4];
    __shared__ int2 stage[P1_CH];      // 32 KB
    const int t  = threadIdx.x;
    const int lane = t & 63, wv = t >> 6;
    const int e0 = blockIdx.x * P1_CH;
    const int cnt = min(P1_CH, N_EDGES - e0);

    int bcv = (t < NBUCK) ? bcnt[t] : 0;   // global bucket counts (ready: prior dispatch)

    hist[t] = 0;
    __syncthreads();

    int2 ed[16];
#pragma unroll
    for (int i = 0; i < 16; ++i) {
        int idx = t + i * 256;
        if (idx < cnt) {
            int s = ei[e0 + idx];
            int d = ei[N_EDGES + e0 + idx];
            ed[i] = make_int2(s, d);
            atomicAdd(&hist[d >> 9], 1);
        }
    }
    __syncthreads();

    // dual scan: A = local hist (scatter layout), B = global bcnt (bucket bases)
    int hv = hist[t];
    int inclA = hv, inclB = bcv;
#pragma unroll
    for (int off = 1; off < 64; off <<= 1) {
        int xa = __shfl_up(inclA, off, 64);
        int xb = __shfl_up(inclB, off, 64);
        if (lane >= off) { inclA += xa; inclB += xb; }
    }
    if (lane == 63) { wtotA[wv] = inclA; wtotB[wv] = inclB; }
    __syncthreads();
    int pA = 0, pB = 0;
    for (int i = 0; i < wv; ++i) { pA += wtotA[i]; pB += wtotB[i]; }
    inclA += pA;
    inclB += pB;
    int exclA = inclA - hv;    // local exclusive
    int exclB = inclB - bcv;   // global bucket base (bbase[t])
    lscan[t] = exclA;
    rank[t]  = exclA;
    if (hv > 0) gbase[t] = exclB + atomicAdd(&boff[t], hv);
    __syncthreads();

#pragma unroll
    for (int i = 0; i < 16; ++i) {
        int idx = t + i * 256;
        if (idx < cnt) {
            int b = ed[i].y >> 9;
            int p = atomicAdd(&rank[b], 1);
            stage[p] = ed[i];
        }
    }
    __syncthreads();

    for (int p = t; p < cnt; p += 256) {
        int2 v = stage[p];
        int b = v.y >> 9;
        tmp[gbase[b] + (p - lscan[b])] = ((unsigned)v.x << 9) | ((unsigned)v.y & 511u);
    }
}

// ---------------------------------------------------------------- phase 2 (fused): counts -> rowptr+dinv, then scatter rec=src<<8
// Inline redundant scan of bcnt for [beg,end) (replaces bbase array).
__global__ __launch_bounds__(256) void bucket_p2(const unsigned* __restrict__ tmp,
                                                 const int* __restrict__ bcnt,
                                                 int* __restrict__ rowptr,
                                                 float* __restrict__ dinv,
                                                 unsigned* __restrict__ rec) {
    __shared__ int cnt[512];
    __shared__ int cur[512];
    __shared__ int wtot[4];
    __shared__ int sbeg, send;
    const int t  = threadIdx.x;
    const int lane = t & 63, wv = t >> 6;
    const int b  = blockIdx.x;
    const int d0 = b << 9;
    const int dend = min(d0 + 512, N_NODES);
    const int nn = dend - d0;

    // scan bcnt to get this bucket's [beg, end)
    int bcv = (t < NBUCK) ? bcnt[t] : 0;
    int binc = wave_incl_scan(bcv, lane);
    if (lane == 63) wtot[wv] = binc;
    cnt[t] = 0;
    cnt[t + 256] = 0;
    __syncthreads();
    {
        int pfx = 0;
        for (int i = 0; i < wv; ++i) pfx += wtot[i];
        binc += pfx;
        if (t == b) { sbeg = binc - bcv; send = binc; }
    }
    __syncthreads();

    const int beg = sbeg;
    const int end = send;
    for (int idx = beg + t; idx < end; idx += 256)
        atomicAdd(&cnt[tmp[idx] & 511u], 1);
    __syncthreads();

    int c0 = cnt[2 * t];
    int c1 = cnt[2 * t + 1];
    int pv = c0 + c1;
    int incl = wave_incl_scan(pv, lane);
    if (lane == 63) wtot[wv] = incl;
    __syncthreads();
    int prefix = 0;
    for (int i = 0; i < wv; ++i) prefix += wtot[i];
    incl += prefix;
    int excl = incl - pv;
    int base0 = beg + excl;
    int base1 = base0 + c0;
    cur[2 * t]     = base0;
    cur[2 * t + 1] = base1;
    if (2 * t < nn) {
        rowptr[d0 + 2 * t] = base0;
        dinv[d0 + 2 * t]   = rsqrtf((float)c0 + 1.0f);
    }
    if (2 * t + 1 < nn) {
        rowptr[d0 + 2 * t + 1] = base1;
        dinv[d0 + 2 * t + 1]   = rsqrtf((float)c1 + 1.0f);
    }
    if (b == NBUCK - 1 && t == 0) rowptr[N_NODES] = N_EDGES;
    __syncthreads();

    for (int idx = beg + t; idx < end; idx += 256) {
        unsigned u = tmp[idx];
        int pos = atomicAdd(&cur[u & 511u], 1);
        rec[pos] = (u >> 9) << 8;       // src byte-offset
    }
}

// ---------------------------------------------------------------- MFMA GEMM, fp32 input (layer 0): out rows scaled by dinv[row]
__global__ __launch_bounds__(256) void gemm_mfma_f(const float* __restrict__ X,
                                                   const unsigned short* __restrict__ Wsw,
                                                   const float* __restrict__ dinv,
                                                   unsigned short* __restrict__ H) {
    __shared__ unsigned short wlds[32 * 512];   // 32 KB
    const int tid   = threadIdx.x;
    const int lane  = tid & 63;
    const int wave  = tid >> 6;
    const int row0w = blockIdx.x * 64 + wave * 16;
    const int m = lane & 15;
    const int q = lane >> 4;

    {
        const uint4* srcp = (const uint4*)Wsw;
        uint4*       dstp = (uint4*)wlds;
#pragma unroll
        for (int i = 0; i < 8; ++i) dstp[tid + i * 256] = srcp[tid + i * 256];
    }
    __syncthreads();

    int r = row0w + m;
    if (r >= N_NODES) r = N_NODES - 1;
    const float* xp = X + (size_t)r * DIM + q * 8;
    f16x8 af[4];
#pragma unroll
    for (int s = 0; s < 4; ++s) {
        float4 x0 = *(const float4*)(xp + s * 32);
        float4 x1 = *(const float4*)(xp + s * 32 + 4);
        f16x8 v;
        v[0] = (_Float16)x0.x; v[1] = (_Float16)x0.y;
        v[2] = (_Float16)x0.z; v[3] = (_Float16)x0.w;
        v[4] = (_Float16)x1.x; v[5] = (_Float16)x1.y;
        v[6] = (_Float16)x1.z; v[7] = (_Float16)x1.w;
        af[s] = v;
    }

    f32x4 acc[8];
    f32x4 z = {0.f, 0.f, 0.f, 0.f};
#pragma unroll
    for (int n = 0; n < 8; ++n) acc[n] = z;

    const unsigned short* wl = wlds + lane * 8;
#pragma unroll
    for (int s = 0; s < 4; ++s)
#pragma unroll
        for (int n = 0; n < 8; ++n) {
            f16x8 wf = *(const f16x8*)(wl + ((n * 4 + s) << 9));
            acc[n] = __builtin_amdgcn_mfma_f32_16x16x32_f16(af[s], wf, acc[n], 0, 0, 0);
        }

#pragma unroll
    for (int j = 0; j < 4; ++j) {
        int row = row0w + q * 4 + j;
        if (row < N_NODES) {
            float dv = dinv[row];
            uint4 o;
            o.x = pack_h2(acc[0][j] * dv, acc[1][j] * dv);
            o.y = pack_h2(acc[2][j] * dv, acc[3][j] * dv);
            o.z = pack_h2(acc[4][j] * dv, acc[5][j] * dv);
            o.w = pack_h2(acc[6][j] * dv, acc[7][j] * dv);
            *(uint4*)(H + (size_t)row * DIM + m * 8) = o;
        } else {
            uint4 zz = make_uint4(0u, 0u, 0u, 0u);   // zero pad rows (gather sentinel)
            *(uint4*)(H + (size_t)row * DIM + m * 8) = zz;
        }
    }
}

// ---------------------------------------------------------------- MFMA GEMM, f16 input (layers 1,2): out rows scaled by dinv[row]
__global__ __launch_bounds__(256) void gemm_mfma_h(const unsigned short* __restrict__ Xh,
                                                   const unsigned short* __restrict__ Wsw,
                                                   const float* __restrict__ dinv,
                                                   unsigned short* __restrict__ H) {
    __shared__ unsigned short wlds[32 * 512];   // 32 KB
    const int tid   = threadIdx.x;
    const int lane  = tid & 63;
    const int wave  = tid >> 6;
    const int row0w = blockIdx.x * 64 + wave * 16;
    const int m = lane & 15;
    const int q = lane >> 4;

    {
        const uint4* srcp = (const uint4*)Wsw;
        uint4*       dstp = (uint4*)wlds;
#pragma unroll
        for (int i = 0; i < 8; ++i) dstp[tid + i * 256] = srcp[tid + i * 256];
    }
    __syncthreads();

    int r = row0w + m;
    if (r >= N_NODES) r = N_NODES - 1;
    const unsigned short* xp = Xh + (size_t)r * DIM + q * 8;
    f16x8 af[4];
#pragma unroll
    for (int s = 0; s < 4; ++s) af[s] = *(const f16x8*)(xp + s * 32);

    f32x4 acc[8];
    f32x4 z = {0.f, 0.f, 0.f, 0.f};
#pragma unroll
    for (int n = 0; n < 8; ++n) acc[n] = z;

    const unsigned short* wl = wlds + lane * 8;
#pragma unroll
    for (int s = 0; s < 4; ++s)
#pragma unroll
        for (int n = 0; n < 8; ++n) {
            f16x8 wf = *(const f16x8*)(wl + ((n * 4 + s) << 9));
            acc[n] = __builtin_amdgcn_mfma_f32_16x16x32_f16(af[s], wf, acc[n], 0, 0, 0);
        }

#pragma unroll
    for (int j = 0; j < 4; ++j) {
        int row = row0w + q * 4 + j;
        if (row < N_NODES) {
            float dv = dinv[row];
            uint4 o;
            o.x = pack_h2(acc[0][j] * dv, acc[1][j] * dv);
            o.y = pack_h2(acc[2][j] * dv, acc[3][j] * dv);
            o.z = pack_h2(acc[4][j] * dv, acc[5][j] * dv);
            o.w = pack_h2(acc[6][j] * dv, acc[7][j] * dv);
            *(uint4*)(H + (size_t)row * DIM + m * 8) = o;
        } else {
            uint4 zz = make_uint4(0u, 0u, 0u, 0u);
            *(uint4*)(H + (size_t)row * DIM + m * 8) = zz;
        }
    }
}

// ---------------------------------------------------------------- fused gather-aggregate + LN + ELU (+ residual), f16
// Quarter-wave per node: 16 lanes own one node; each lane owns bytes l16*16..+15.
__global__ __launch_bounds__(256) void agg_ln(const unsigned short* __restrict__ Hh,
                                              const unsigned short* __restrict__ xin,
                                              const float* __restrict__ dinv,
                                              const float* __restrict__ bias,
                                              const float* __restrict__ g,
                                              const float* __restrict__ be,
                                              const int* __restrict__ rowptr,
                                              const unsigned* __restrict__ rec,
                                              unsigned short* __restrict__ outb) {
    const int tid  = threadIdx.x;
    const int lane = tid & 63;
    const int l16  = tid & 15;
    const int gb   = lane & 48;                  // group base lane within wave
    const int node = blockIdx.x * 16 + (tid >> 4);
    const int beg  = rowptr[node];
    const int end  = rowptr[node + 1];
    const char* Hb8 = (const char*)Hh;
    const unsigned laneoff = (unsigned)l16 * 16;       // byte offset within row
    const unsigned sentin  = (unsigned)N_NODES << 8;   // zero row

    f16x2 accA[4], accB[4], accC[4], accD[4];
    f16x2 hz = {(_Float16)0.f, (_Float16)0.f};
#pragma unroll
    for (int k = 0; k < 4; ++k) { accA[k] = hz; accB[k] = hz; accC[k] = hz; accD[k] = hz; }

    for (int e0 = beg; e0 < end; e0 += 16) {
        int cnt = min(end - e0, 16);
        unsigned sv = (l16 < cnt) ? rec[e0 + l16] : sentin;
        int cntR = (cnt + 7) & ~7;
        for (int j = 0; j < cntR; j += 8) {
            unsigned o0 = (unsigned)__shfl((int)sv, gb + j + 0, 64) + laneoff;
            unsigned o1 = (unsigned)__shfl((int)sv, gb + j + 1, 64) + laneoff;
            unsigned o2 = (unsigned)__shfl((int)sv, gb + j + 2, 64) + laneoff;
            unsigned o3 = (unsigned)__shfl((int)sv, gb + j + 3, 64) + laneoff;
            unsigned o4 = (unsigned)__shfl((int)sv, gb + j + 4, 64) + laneoff;
            unsigned o5 = (unsigned)__shfl((int)sv, gb + j + 5, 64) + laneoff;
            unsigned o6 = (unsigned)__shfl((int)sv, gb + j + 6, 64) + laneoff;
            unsigned o7 = (unsigned)__shfl((int)sv, gb + j + 7, 64) + laneoff;
            uint4 u0 = *(const uint4*)(Hb8 + o0);
            uint4 u1 = *(const uint4*)(Hb8 + o1);
            uint4 u2 = *(const uint4*)(Hb8 + o2);
            uint4 u3 = *(const uint4*)(Hb8 + o3);
            uint4 u4 = *(const uint4*)(Hb8 + o4);
            uint4 u5 = *(const uint4*)(Hb8 + o5);
            uint4 u6 = *(const uint4*)(Hb8 + o6);
            uint4 u7 = *(const uint4*)(Hb8 + o7);
            accA[0] += as_h2(u0.x); accA[1] += as_h2(u0.y); accA[2] += as_h2(u0.z); accA[3] += as_h2(u0.w);
            accB[0] += as_h2(u1.x); accB[1] += as_h2(u1.y); accB[2] += as_h2(u1.z); accB[3] += as_h2(u1.w);
            accC[0] += as_h2(u2.x); accC[1] += as_h2(u2.y); accC[2] += as_h2(u2.z); accC[3] += as_h2(u2.w);
            accD[0] += as_h2(u3.x); accD[1] += as_h2(u3.y); accD[2] += as_h2(u3.z); accD[3] += as_h2(u3.w);
            accA[0] += as_h2(u4.x); accA[1] += as_h2(u4.y); accA[2] += as_h2(u4.z); accA[3] += as_h2(u4.w);
            accB[0] += as_h2(u5.x); accB[1] += as_h2(u5.y); accB[2] += as_h2(u5.z); accB[3] += as_h2(u5.w);
            accC[0] += as_h2(u6.x); accC[1] += as_h2(u6.y); accC[2] += as_h2(u6.z); accC[3] += as_h2(u6.w);
            accD[0] += as_h2(u7.x); accD[1] += as_h2(u7.y); accD[2] += as_h2(u7.z); accD[3] += as_h2(u7.w);
        }
    }

#pragma unroll
    for (int k = 0; k < 4; ++k) accA[k] = (accA[k] + accB[k]) + (accC[k] + accD[k]);

    const float dv = dinv[node];
    const unsigned nodeoff = ((unsigned)node << 8) + laneoff;
    uint4 hv = *(const uint4*)(Hb8 + nodeoff);       // h'[node] (pre-scaled)
    const int c0 = l16 * 8;
    float4 bb0 = *(const float4*)(bias + c0);
    float4 bb1 = *(const float4*)(bias + c0 + 4);
    f16x2 h0 = as_h2(hv.x), h1 = as_h2(hv.y), h2 = as_h2(hv.z), h3 = as_h2(hv.w);

    float a[8];
    a[0] = ((float)accA[0].x + (float)h0.x) * dv + bb0.x;
    a[1] = ((float)accA[0].y + (float)h0.y) * dv + bb0.y;
    a[2] = ((float)accA[1].x + (float)h1.x) * dv + bb0.z;
    a[3] = ((float)accA[1].y + (float)h1.y) * dv + bb0.w;
    a[4] = ((float)accA[2].x + (float)h2.x) * dv + bb1.x;
    a[5] = ((float)accA[2].y + (float)h2.y) * dv + bb1.y;
    a[6] = ((float)accA[3].x + (float)h3.x) * dv + bb1.z;
    a[7] = ((float)accA[3].y + (float)h3.y) * dv + bb1.w;

    float s1 = 0.f, s2 = 0.f;
#pragma unroll
    for (int i = 0; i < 8; ++i) { s1 += a[i]; s2 += a[i] * a[i]; }
#pragma unroll
    for (int mk = 1; mk <= 8; mk <<= 1) {
        s1 += __shfl_xor(s1, mk, 64);
        s2 += __shfl_xor(s2, mk, 64);
    }
    float mean = s1 * (1.0f / 128.0f);
    float var  = s2 * (1.0f / 128.0f) - mean * mean;
    float rr   = rsqrtf(var + 1e-5f);

    float4 gg0 = *(const float4*)(g + c0);
    float4 gg1 = *(const float4*)(g + c0 + 4);
    float4 ee0 = *(const float4*)(be + c0);
    float4 ee1 = *(const float4*)(be + c0 + 4);

    float r[8];
    r[0] = (a[0] - mean) * rr * gg0.x + ee0.x;
    r[1] = (a[1] - mean) * rr * gg0.y + ee0.y;
    r[2] = (a[2] - mean) * rr * gg0.z + ee0.z;
    r[3] = (a[3] - mean) * rr * gg0.w + ee0.w;
    r[4] = (a[4] - mean) * rr * gg1.x + ee1.x;
    r[5] = (a[5] - mean) * rr * gg1.y + ee1.y;
    r[6] = (a[6] - mean) * rr * gg1.z + ee1.z;
    r[7] = (a[7] - mean) * rr * gg1.w + ee1.w;
#pragma unroll
    for (int i = 0; i < 8; ++i) r[i] = r[i] > 0.0f ? r[i] : expm1f(r[i]);

    if (xin) {
        uint4 xv = *(const uint4*)((const char*)xin + nodeoff);
        f16x2 x0 = as_h2(xv.x), x1 = as_h2(xv.y), x2 = as_h2(xv.z), x3 = as_h2(xv.w);
        r[0] += (float)x0.x; r[1] += (float)x0.y;
        r[2] += (float)x1.x; r[3] += (float)x1.y;
        r[4] += (float)x2.x; r[5] += (float)x2.y;
        r[6] += (float)x3.x; r[7] += (float)x3.y;
    }

    uint4 o;
    o.x = pack_h2(r[0], r[1]);
    o.y = pack_h2(r[2], r[3]);
    o.z = pack_h2(r[4], r[5]);
    o.w = pack_h2(r[6], r[7]);
    *(uint4*)((char*)outb + nodeoff) = o;
}

// ---------------------------------------------------------------- layer-2 agg + LN + ELU + residual + CLASSIFIER (fused)
// Same as agg_ln but the 16 LN rows go to LDS; wave 0 runs the 12 classifier
// MFMAs and writes f32 logits. Ch is never materialized.
__global__ __launch_bounds__(256) void agg_ln_cls(const unsigned short* __restrict__ Hh,
                                                  const unsigned short* __restrict__ xin,
                                                  const float* __restrict__ dinv,
                                                  const float* __restrict__ bias,
                                                  const float* __restrict__ g,
                                                  const float* __restrict__ be,
                                                  const int* __restrict__ rowptr,
                                                  const unsigned* __restrict__ rec,
                                                  const unsigned short* __restrict__ Wcsw,
                                                  const float* __restrict__ bc,
                                                  float* __restrict__ out) {
    __shared__ _Float16 hl[16][136];   // 136-pad: 16B-aligned rows, 2-way-bank-free MFMA reads
    const int tid  = threadIdx.x;
    const int lane = tid & 63;
    const int l16  = tid & 15;
    const int gb   = lane & 48;
    const int grp  = tid >> 4;
    const int node0 = blockIdx.x * 16;
    const int node = node0 + grp;
    const int beg  = rowptr[node];
    const int end  = rowptr[node + 1];
    const char* Hb8 = (const char*)Hh;
    const unsigned laneoff = (unsigned)l16 * 16;
    const unsigned sentin  = (unsigned)N_NODES << 8;

    f16x2 accA[4], accB[4], accC[4], accD[4];
    f16x2 hz = {(_Float16)0.f, (_Float16)0.f};
#pragma unroll
    for (int k = 0; k < 4; ++k) { accA[k] = hz; accB[k] = hz; accC[k] = hz; accD[k] = hz; }

    for (int e0 = beg; e0 < end; e0 += 16) {
        int cnt = min(end - e0, 16);
        unsigned sv = (l16 < cnt) ? rec[e0 + l16] : sentin;
        int cntR = (cnt + 7) & ~7;
        for (int j = 0; j < cntR; j += 8) {
            unsigned o0 = (unsigned)__shfl((int)sv, gb + j + 0, 64) + laneoff;
            unsigned o1 = (unsigned)__shfl((int)sv, gb + j + 1, 64) + laneoff;
            unsigned o2 = (unsigned)__shfl((int)sv, gb + j + 2, 64) + laneoff;
            unsigned o3 = (unsigned)__shfl((int)sv, gb + j + 3, 64) + laneoff;
            unsigned o4 = (unsigned)__shfl((int)sv, gb + j + 4, 64) + laneoff;
            unsigned o5 = (unsigned)__shfl((int)sv, gb + j + 5, 64) + laneoff;
            unsigned o6 = (unsigned)__shfl((int)sv, gb + j + 6, 64) + laneoff;
            unsigned o7 = (unsigned)__shfl((int)sv, gb + j + 7, 64) + laneoff;
            uint4 u0 = *(const uint4*)(Hb8 + o0);
            uint4 u1 = *(const uint4*)(Hb8 + o1);
            uint4 u2 = *(const uint4*)(Hb8 + o2);
            uint4 u3 = *(const uint4*)(Hb8 + o3);
            uint4 u4 = *(const uint4*)(Hb8 + o4);
            uint4 u5 = *(const uint4*)(Hb8 + o5);
            uint4 u6 = *(const uint4*)(Hb8 + o6);
            uint4 u7 = *(const uint4*)(Hb8 + o7);
            accA[0] += as_h2(u0.x); accA[1] += as_h2(u0.y); accA[2] += as_h2(u0.z); accA[3] += as_h2(u0.w);
            accB[0] += as_h2(u1.x); accB[1] += as_h2(u1.y); accB[2] += as_h2(u1.z); accB[3] += as_h2(u1.w);
            accC[0] += as_h2(u2.x); accC[1] += as_h2(u2.y); accC[2] += as_h2(u2.z); accC[3] += as_h2(u2.w);
            accD[0] += as_h2(u3.x); accD[1] += as_h2(u3.y); accD[2] += as_h2(u3.z); accD[3] += as_h2(u3.w);
            accA[0] += as_h2(u4.x); accA[1] += as_h2(u4.y); accA[2] += as_h2(u4.z); accA[3] += as_h2(u4.w);
            accB[0] += as_h2(u5.x); accB[1] += as_h2(u5.y); accB[2] += as_h2(u5.z); accB[3] += as_h2(u5.w);
            accC[0] += as_h2(u6.x); accC[1] += as_h2(u6.y); accC[2] += as_h2(u6.z); accC[3] += as_h2(u6.w);
            accD[0] += as_h2(u7.x); accD[1] += as_h2(u7.y); accD[2] += as_h2(u7.z); accD[3] += as_h2(u7.w);
        }
    }

#pragma unroll
    for (int k = 0; k < 4; ++k) accA[k] = (accA[k] + accB[k]) + (accC[k] + accD[k]);

    const float dv = dinv[node];
    const unsigned nodeoff = ((unsigned)node << 8) + laneoff;
    uint4 hv = *(const uint4*)(Hb8 + nodeoff);
    const int c0 = l16 * 8;
    float4 bb0 = *(const float4*)(bias + c0);
    float4 bb1 = *(const float4*)(bias + c0 + 4);
    f16x2 h0 = as_h2(hv.x), h1 = as_h2(hv.y), h2 = as_h2(hv.z), h3 = as_h2(hv.w);

    float a[8];
    a[0] = ((float)accA[0].x + (float)h0.x) * dv + bb0.x;
    a[1] = ((float)accA[0].y + (float)h0.y) * dv + bb0.y;
    a[2] = ((float)accA[1].x + (float)h1.x) * dv + bb0.z;
    a[3] = ((float)accA[1].y + (float)h1.y) * dv + bb0.w;
    a[4] = ((float)accA[2].x + (float)h2.x) * dv + bb1.x;
    a[5] = ((float)accA[2].y + (float)h2.y) * dv + bb1.y;
    a[6] = ((float)accA[3].x + (float)h3.x) * dv + bb1.z;
    a[7] = ((float)accA[3].y + (float)h3.y) * dv + bb1.w;

    float s1 = 0.f, s2 = 0.f;
#pragma unroll
    for (int i = 0; i < 8; ++i) { s1 += a[i]; s2 += a[i] * a[i]; }
#pragma unroll
    for (int mk = 1; mk <= 8; mk <<= 1) {
        s1 += __shfl_xor(s1, mk, 64);
        s2 += __shfl_xor(s2, mk, 64);
    }
    float mean = s1 * (1.0f / 128.0f);
    float var  = s2 * (1.0f / 128.0f) - mean * mean;
    float rr   = rsqrtf(var + 1e-5f);

    float4 gg0 = *(const float4*)(g + c0);
    float4 gg1 = *(const float4*)(g + c0 + 4);
    float4 ee0 = *(const float4*)(be + c0);
    float4 ee1 = *(const float4*)(be + c0 + 4);

    float r[8];
    r[0] = (a[0] - mean) * rr * gg0.x + ee0.x;
    r[1] = (a[1] - mean) * rr * gg0.y + ee0.y;
    r[2] = (a[2] - mean) * rr * gg0.z + ee0.z;
    r[3] = (a[3] - mean) * rr * gg0.w + ee0.w;
    r[4] = (a[4] - mean) * rr * gg1.x + ee1.x;
    r[5] = (a[5] - mean) * rr * gg1.y + ee1.y;
    r[6] = (a[6] - mean) * rr * gg1.z + ee1.z;
    r[7] = (a[7] - mean) * rr * gg1.w + ee1.w;
#pragma unroll
    for (int i = 0; i < 8; ++i) r[i] = r[i] > 0.0f ? r[i] : expm1f(r[i]);

    if (xin) {
        uint4 xv = *(const uint4*)((const char*)xin + nodeoff);
        f16x2 x0 = as_h2(xv.x), x1 = as_h2(xv.y), x2 = as_h2(xv.z), x3 = as_h2(xv.w);
        r[0] += (float)x0.x; r[1] += (float)x0.y;
        r[2] += (float)x1.x; r[3] += (float)x1.y;
        r[4] += (float)x2.x; r[5] += (float)x2.y;
        r[6] += (float)x3.x; r[7] += (float)x3.y;
    }

    uint4 o;
    o.x = pack_h2(r[0], r[1]);
    o.y = pack_h2(r[2], r[3]);
    o.z = pack_h2(r[4], r[5]);
    o.w = pack_h2(r[6], r[7]);
    *(uint4*)&hl[grp][l16 * 8] = o;
    __syncthreads();

    if (tid < 64) {
        const int m = lane & 15;
        const int q = lane >> 4;

        f16x8 wf[12];
#pragma unroll
        for (int f = 0; f < 12; ++f)
            wf[f] = *(const f16x8*)(Wcsw + (f << 9) + lane * 8);

        f16x8 af[4];
#pragma unroll
        for (int s = 0; s < 4; ++s)
            af[s] = *(const f16x8*)&hl[m][q * 8 + s * 32];

        f32x4 acc[3];
        f32x4 z = {0.f, 0.f, 0.f, 0.f};
#pragma unroll
        for (int n = 0; n < 3; ++n) acc[n] = z;

#pragma unroll
        for (int s = 0; s < 4; ++s)
#pragma unroll
            for (int n = 0; n < 3; ++n)
                acc[n] = __builtin_amdgcn_mfma_f32_16x16x32_f16(af[s], wf[n * 4 + s], acc[n], 0, 0, 0);

#pragma unroll
        for (int j = 0; j < 4; ++j) {
            int row = node0 + q * 4 + j;
#pragma unroll
            for (int n = 0; n < 3; ++n) {
                int c = 3 * m + n;
                if (c < NCLS)
                    out[(size_t)row * NCLS + c] = acc[n][j] + bc[c];
            }
        }
    }
}

// ---------------------------------------------------------------- launch
extern "C" void kernel_launch(void* const* d_in, const int* in_sizes, int n_in,
                              void* d_out, int out_size, void* d_ws, size_t ws_size,
                              hipStream_t stream) {
    const float* x  = (const float*)d_in[0];
    const int*   ei = (const int*)d_in[1];
    const float* W[3]  = {(const float*)d_in[2], (const float*)d_in[6], (const float*)d_in[10]};
    const float* b[3]  = {(const float*)d_in[3], (const float*)d_in[7], (const float*)d_in[11]};
    const float* g[3]  = {(const float*)d_in[4], (const float*)d_in[8], (const float*)d_in[12]};
    const float* be[3] = {(const float*)d_in[5], (const float*)d_in[9], (const float*)d_in[13]};
    const float* Wc = (const float*)d_in[14];
    const float* bc = (const float*)d_in[15];
    float* out = (float*)d_out;

    char* ws = (char*)d_ws;
    const size_t NP = 400128;  // padded (N+1)*4 bytes
    float* dinv   = (float*)(ws);
    int*   rowptr = (int*)  (ws + NP);
    int*   bcnt   = (int*)  (ws + 2 * NP);
    int*   boff   = (int*)  (ws + 2 * NP + 1024);
    unsigned* rec = (unsigned*)(ws + 2 * NP + 4096);
    unsigned short* Hh = (unsigned short*)(ws + 2 * NP + 4096 + (size_t)N_EDGES * 8);
    unsigned short* Ah = Hh + (size_t)(N_NODES + 64) * DIM;   // Hh has zero-pad rows
    unsigned short* Ch = Ah + (size_t)N_NODES * DIM;
    unsigned short* Wsw0 = Ch + (size_t)N_NODES * DIM;
    unsigned short* Wsw1 = Wsw0 + DIM * DIM;
    unsigned short* Wsw2 = Wsw1 + DIM * DIM;
    unsigned short* Wcsw = Wsw2 + DIM * DIM;   // 12*512 shorts
    unsigned* tmp = (unsigned*)Ch;             // aliases Ch; dead before layer 0 writes Ch

    // ---- setup: zero bcnt+boff (memset) + swizzles + bucket histogram (1 dispatch) ----
    hipMemsetAsync(bcnt, 0, 2048, stream);
    setup_misc<<<216 + P1_GRID, 256, 0, stream>>>(W[0], W[1], W[2], Wc, ei,
                                                  Wsw0, Wsw1, Wsw2, Wcsw, bcnt);

    // ---- CSR build (inline-scan: no bscan dispatch) ----
    bucket_p1<<<P1_GRID, 256, 0, stream>>>(ei, bcnt, boff, tmp);
    bucket_p2<<<NBUCK, 256, 0, stream>>>(tmp, bcnt, rowptr, dinv, rec);

    const int gemm_grid = (N_NODES + 63) / 64;    // 1563 (covers pad rows to 100032)
    const int agg_grid  = N_NODES / 16;           // 6250 (16 nodes/block, quarter-wave each)

    // layer 0: x fp32 -> Hh (scaled); agg -> Ch
    gemm_mfma_f<<<gemm_grid, 256, 0, stream>>>(x, Wsw0, dinv, Hh);
    agg_ln<<<agg_grid, 256, 0, stream>>>(Hh, nullptr, dinv, b[0], g[0], be[0], rowptr, rec, Ch);

    // layer 1: Ch -> Hh (scaled); agg (+resid Ch) -> Ah
    gemm_mfma_h<<<gemm_grid, 256, 0, stream>>>(Ch, Wsw1, dinv, Hh);
    agg_ln<<<agg_grid, 256, 0, stream>>>(Hh, Ch, dinv, b[1], g[1], be[1], rowptr, rec, Ah);

    // layer 2: Ah -> Hh (scaled); agg (+resid Ah) + classifier -> out (Ch never written)
    gemm_mfma_h<<<gemm_grid, 256, 0, stream>>>(Ah, Wsw2, dinv, Hh);
    agg_ln_cls<<<agg_grid, 256, 0, stream>>>(Hh, Ah, dinv, b[2], g[2], be[2], rowptr, rec,
                                             Wcsw, bc, out);
}

// Round 3
// 372.234 us; speedup vs baseline: 1.1040x; 1.0461x over previous
//
#include <hip/hip_runtime.h>
#include <math.h>

#define N_NODES 100000
#define N_EDGES 1600000
#define DIM     128
#define NCLS    40
#define NBUCK   196      // ceil(100000/512) buckets of 512 nodes
#define P1_CH   4096     // edges per phase-1 block
#define P1_GRID 391      // ceil(1600000/4096)

typedef _Float16 f16x8 __attribute__((ext_vector_type(8)));
typedef _Float16 f16x2 __attribute__((ext_vector_type(2)));
typedef float    f32x4 __attribute__((ext_vector_type(4)));

__device__ inline unsigned short f16bits(float f) {
    union { _Float16 h; unsigned short u; } cv;
    cv.h = (_Float16)f;
    return cv.u;
}
__device__ inline f16x2 as_h2(unsigned u) {
    union { unsigned u; f16x2 h; } cv;
    cv.u = u;
    return cv.h;
}
__device__ inline unsigned as_u(f16x2 h) {
    union { f16x2 h; unsigned u; } cv;
    cv.h = h;
    return cv.u;
}
__device__ inline unsigned pack_h2(float lo, float hi) {
    f16x2 h;
    h.x = (_Float16)lo;
    h.y = (_Float16)hi;
    return as_u(h);
}
__device__ inline int wave_incl_scan(int v, int lane) {
#pragma unroll
    for (int off = 1; off < 64; off <<= 1) {
        int x = __shfl_up(v, off, 64);
        if (lane >= off) v += x;
    }
    return v;
}

// ---------------------------------------------------------------- setup: W swizzles + bucket histogram + H2 pad-zero
__global__ __launch_bounds__(256) void setup_misc(const float* __restrict__ W0,
                                                  const float* __restrict__ W1,
                                                  const float* __restrict__ W2,
                                                  const float* __restrict__ Wc,
                                                  const int* __restrict__ ei,
                                                  unsigned short* __restrict__ Wsw0,
                                                  unsigned short* __restrict__ Wsw1,
                                                  unsigned short* __restrict__ Wsw2,
                                                  unsigned short* __restrict__ Wcsw,
                                                  int* __restrict__ bcnt,
                                                  unsigned short* __restrict__ H2) {
    int blk = blockIdx.x;
    if (blk < 192) {
        const float* W = (blk < 64) ? W0 : (blk < 128) ? W1 : W2;
        unsigned short* Wsw = (blk < 64) ? Wsw0 : (blk < 128) ? Wsw1 : Wsw2;
        int o = (blk & 63) * 256 + threadIdx.x;  // 0..16383
        int f = o >> 9;
        int l = (o >> 3) & 63;
        int j = o & 7;
        int n = f >> 2;
        int s = f & 3;
        int k = s * 32 + (l >> 4) * 8 + j;
        int c = (l & 15) * 8 + n;
        Wsw[o] = f16bits(W[k * DIM + c]);
    } else if (blk < 216) {
        int o = (blk - 192) * 256 + threadIdx.x; // 0..6143
        int f = o >> 9;
        int l = (o >> 3) & 63;
        int j = o & 7;
        int n = f >> 2;
        int s = f & 3;
        int k = s * 32 + (l >> 4) * 8 + j;
        int c = (l & 15) * 3 + n;
        Wcsw[o] = (c < NCLS) ? f16bits(Wc[k * NCLS + c]) : (unsigned short)0;
    } else if (blk < 216 + P1_GRID) {
        __shared__ int h[256];
        const int t  = threadIdx.x;
        const int e0 = (blk - 216) * P1_CH;
        const int cnt = min(P1_CH, N_EDGES - e0);
        h[t] = 0;
        __syncthreads();
        for (int i = t; i < cnt; i += 256)
            atomicAdd(&h[ei[N_EDGES + e0 + i] >> 9], 1);
        __syncthreads();
        if (h[t]) atomicAdd(&bcnt[t], h[t]);
    } else {
        // zero H2 pad rows (gather sentinel target): rows N..N+31
        uint4* p = (uint4*)(H2 + (size_t)N_NODES * DIM);
        uint4 zz = make_uint4(0u, 0u, 0u, 0u);
#pragma unroll
        for (int i = 0; i < 4; ++i) p[threadIdx.x + i * 256] = zz;   // 1024 uint4 = 32 rows
    }
}

// ---------------------------------------------------------------- phase 1: bucket edges by dst>>9 into packed tmp
// Inline redundant scan of bcnt (replaces bscan dispatch); global alloc via boff atomics.
// tmp entry = (s<<9) | (d & 511)
__global__ __launch_bounds__(256) void bucket_p1(const int* __restrict__ ei,
                                                 const int* __restrict__ bcnt,
                                                 int* __restrict__ boff,
                                                 unsigned* __restrict__ tmp) {
    __shared__ int  hist[256];
    __shared__ int  lscan[256];
    __shared__ int  rank[256];
    __shared__ int  gbase[256];
    __shared__ int  wtotA[4];
    __shared__ int  wtotB[4];
    __shared__ int2 stage[P1_CH];      // 32 KB
    const int t  = threadIdx.x;
    const int lane = t & 63, wv = t >> 6;
    const int e0 = blockIdx.x * P1_CH;
    const int cnt = min(P1_CH, N_EDGES - e0);

    int bcv = (t < NBUCK) ? bcnt[t] : 0;   // global bucket counts (ready: prior dispatch)

    hist[t] = 0;
    __syncthreads();

    int2 ed[16];
#pragma unroll
    for (int i = 0; i < 16; ++i) {
        int idx = t + i * 256;
        if (idx < cnt) {
            int s = ei[e0 + idx];
            int d = ei[N_EDGES + e0 + idx];
            ed[i] = make_int2(s, d);
            atomicAdd(&hist[d >> 9], 1);
        }
    }
    __syncthreads();

    // dual scan: A = local hist (scatter layout), B = global bcnt (bucket bases)
    int hv = hist[t];
    int inclA = hv, inclB = bcv;
#pragma unroll
    for (int off = 1; off < 64; off <<= 1) {
        int xa = __shfl_up(inclA, off, 64);
        int xb = __shfl_up(inclB, off, 64);
        if (lane >= off) { inclA += xa; inclB += xb; }
    }
    if (lane == 63) { wtotA[wv] = inclA; wtotB[wv] = inclB; }
    __syncthreads();
    int pA = 0, pB = 0;
    for (int i = 0; i < wv; ++i) { pA += wtotA[i]; pB += wtotB[i]; }
    inclA += pA;
    inclB += pB;
    int exclA = inclA - hv;    // local exclusive
    int exclB = inclB - bcv;   // global bucket base (bbase[t])
    lscan[t] = exclA;
    rank[t]  = exclA;
    if (hv > 0) gbase[t] = exclB + atomicAdd(&boff[t], hv);
    __syncthreads();

#pragma unroll
    for (int i = 0; i < 16; ++i) {
        int idx = t + i * 256;
        if (idx < cnt) {
            int b = ed[i].y >> 9;
            int p = atomicAdd(&rank[b], 1);
            stage[p] = ed[i];
        }
    }
    __syncthreads();

    for (int p = t; p < cnt; p += 256) {
        int2 v = stage[p];
        int b = v.y >> 9;
        tmp[gbase[b] + (p - lscan[b])] = ((unsigned)v.x << 9) | ((unsigned)v.y & 511u);
    }
}

// ---------------------------------------------------------------- phase 2 (fused): counts -> rowptr+dinv, then scatter rec=src<<8
__global__ __launch_bounds__(256) void bucket_p2(const unsigned* __restrict__ tmp,
                                                 const int* __restrict__ bcnt,
                                                 int* __restrict__ rowptr,
                                                 float* __restrict__ dinv,
                                                 unsigned* __restrict__ rec) {
    __shared__ int cnt[512];
    __shared__ int cur[512];
    __shared__ int wtot[4];
    __shared__ int sbeg, send;
    const int t  = threadIdx.x;
    const int lane = t & 63, wv = t >> 6;
    const int b  = blockIdx.x;
    const int d0 = b << 9;
    const int dend = min(d0 + 512, N_NODES);
    const int nn = dend - d0;

    // scan bcnt to get this bucket's [beg, end)
    int bcv = (t < NBUCK) ? bcnt[t] : 0;
    int binc = wave_incl_scan(bcv, lane);
    if (lane == 63) wtot[wv] = binc;
    cnt[t] = 0;
    cnt[t + 256] = 0;
    __syncthreads();
    {
        int pfx = 0;
        for (int i = 0; i < wv; ++i) pfx += wtot[i];
        binc += pfx;
        if (t == b) { sbeg = binc - bcv; send = binc; }
    }
    __syncthreads();

    const int beg = sbeg;
    const int end = send;
    for (int idx = beg + t; idx < end; idx += 256)
        atomicAdd(&cnt[tmp[idx] & 511u], 1);
    __syncthreads();

    int c0 = cnt[2 * t];
    int c1 = cnt[2 * t + 1];
    int pv = c0 + c1;
    int incl = wave_incl_scan(pv, lane);
    if (lane == 63) wtot[wv] = incl;
    __syncthreads();
    int prefix = 0;
    for (int i = 0; i < wv; ++i) prefix += wtot[i];
    incl += prefix;
    int excl = incl - pv;
    int base0 = beg + excl;
    int base1 = base0 + c0;
    cur[2 * t]     = base0;
    cur[2 * t + 1] = base1;
    if (2 * t < nn) {
        rowptr[d0 + 2 * t] = base0;
        dinv[d0 + 2 * t]   = rsqrtf((float)c0 + 1.0f);
    }
    if (2 * t + 1 < nn) {
        rowptr[d0 + 2 * t + 1] = base1;
        dinv[d0 + 2 * t + 1]   = rsqrtf((float)c1 + 1.0f);
    }
    if (b == NBUCK - 1 && t == 0) rowptr[N_NODES] = N_EDGES;
    __syncthreads();

    for (int idx = beg + t; idx < end; idx += 256) {
        unsigned u = tmp[idx];
        int pos = atomicAdd(&cur[u & 511u], 1);
        rec[pos] = (u >> 9) << 8;       // src byte-offset
    }
}

// ---------------------------------------------------------------- MFMA GEMM, fp32 input (layer 0): out rows scaled by dinv[row]
__global__ __launch_bounds__(256) void gemm_mfma_f(const float* __restrict__ X,
                                                   const unsigned short* __restrict__ Wsw,
                                                   const float* __restrict__ dinv,
                                                   unsigned short* __restrict__ H) {
    __shared__ unsigned short wlds[32 * 512];   // 32 KB
    const int tid   = threadIdx.x;
    const int lane  = tid & 63;
    const int wave  = tid >> 6;
    const int row0w = blockIdx.x * 64 + wave * 16;
    const int m = lane & 15;
    const int q = lane >> 4;

    {
        const uint4* srcp = (const uint4*)Wsw;
        uint4*       dstp = (uint4*)wlds;
#pragma unroll
        for (int i = 0; i < 8; ++i) dstp[tid + i * 256] = srcp[tid + i * 256];
    }
    __syncthreads();

    int r = row0w + m;
    if (r >= N_NODES) r = N_NODES - 1;
    const float* xp = X + (size_t)r * DIM + q * 8;
    f16x8 af[4];
#pragma unroll
    for (int s = 0; s < 4; ++s) {
        float4 x0 = *(const float4*)(xp + s * 32);
        float4 x1 = *(const float4*)(xp + s * 32 + 4);
        f16x8 v;
        v[0] = (_Float16)x0.x; v[1] = (_Float16)x0.y;
        v[2] = (_Float16)x0.z; v[3] = (_Float16)x0.w;
        v[4] = (_Float16)x1.x; v[5] = (_Float16)x1.y;
        v[6] = (_Float16)x1.z; v[7] = (_Float16)x1.w;
        af[s] = v;
    }

    f32x4 acc[8];
    f32x4 z = {0.f, 0.f, 0.f, 0.f};
#pragma unroll
    for (int n = 0; n < 8; ++n) acc[n] = z;

    const unsigned short* wl = wlds + lane * 8;
#pragma unroll
    for (int s = 0; s < 4; ++s)
#pragma unroll
        for (int n = 0; n < 8; ++n) {
            f16x8 wf = *(const f16x8*)(wl + ((n * 4 + s) << 9));
            acc[n] = __builtin_amdgcn_mfma_f32_16x16x32_f16(af[s], wf, acc[n], 0, 0, 0);
        }

#pragma unroll
    for (int j = 0; j < 4; ++j) {
        int row = row0w + q * 4 + j;
        if (row < N_NODES) {
            float dv = dinv[row];
            uint4 o;
            o.x = pack_h2(acc[0][j] * dv, acc[1][j] * dv);
            o.y = pack_h2(acc[2][j] * dv, acc[3][j] * dv);
            o.z = pack_h2(acc[4][j] * dv, acc[5][j] * dv);
            o.w = pack_h2(acc[6][j] * dv, acc[7][j] * dv);
            *(uint4*)(H + (size_t)row * DIM + m * 8) = o;
        } else {
            uint4 zz = make_uint4(0u, 0u, 0u, 0u);   // zero pad rows (gather sentinel)
            *(uint4*)(H + (size_t)row * DIM + m * 8) = zz;
        }
    }
}

// ---------------------------------------------------------------- fused agg + LN + ELU (+resid) + NEXT-LAYER GEMM
// Quarter-wave per node. LN output rows -> Cout (residual for next layer) and
// LDS tile; then all 4 waves run the 16x128 x 128x128 GEMM (2 col-tiles each),
// scale by dinv[row], write Hout (next layer's gather source, != gather buffer).
__global__ __launch_bounds__(256) void agg_ln_gemm(const unsigned short* __restrict__ Hh,
                                                   const unsigned short* __restrict__ xin,
                                                   const float* __restrict__ dinv,
                                                   const float* __restrict__ bias,
                                                   const float* __restrict__ g,
                                                   const float* __restrict__ be,
                                                   const int* __restrict__ rowptr,
                                                   const unsigned* __restrict__ rec,
                                                   const unsigned short* __restrict__ Wsw,
                                                   unsigned short* __restrict__ Cout,
                                                   unsigned short* __restrict__ Hout) {
    __shared__ _Float16 hl[16][136];
    const int tid  = threadIdx.x;
    const int lane = tid & 63;
    const int l16  = tid & 15;
    const int gb   = lane & 48;
    const int grp  = tid >> 4;
    const int wave = tid >> 6;
    const int node0 = blockIdx.x * 16;
    const int node = node0 + grp;
    const int beg  = rowptr[node];
    const int end  = rowptr[node + 1];
    const char* Hb8 = (const char*)Hh;
    const unsigned laneoff = (unsigned)l16 * 16;
    const unsigned sentin  = (unsigned)N_NODES << 8;

    f16x2 accA[4], accB[4], accC[4], accD[4];
    f16x2 hz = {(_Float16)0.f, (_Float16)0.f};
#pragma unroll
    for (int k = 0; k < 4; ++k) { accA[k] = hz; accB[k] = hz; accC[k] = hz; accD[k] = hz; }

    for (int e0 = beg; e0 < end; e0 += 16) {
        int cnt = min(end - e0, 16);
        unsigned sv = (l16 < cnt) ? rec[e0 + l16] : sentin;
        int cntR = (cnt + 7) & ~7;
        for (int j = 0; j < cntR; j += 8) {
            unsigned o0 = (unsigned)__shfl((int)sv, gb + j + 0, 64) + laneoff;
            unsigned o1 = (unsigned)__shfl((int)sv, gb + j + 1, 64) + laneoff;
            unsigned o2 = (unsigned)__shfl((int)sv, gb + j + 2, 64) + laneoff;
            unsigned o3 = (unsigned)__shfl((int)sv, gb + j + 3, 64) + laneoff;
            unsigned o4 = (unsigned)__shfl((int)sv, gb + j + 4, 64) + laneoff;
            unsigned o5 = (unsigned)__shfl((int)sv, gb + j + 5, 64) + laneoff;
            unsigned o6 = (unsigned)__shfl((int)sv, gb + j + 6, 64) + laneoff;
            unsigned o7 = (unsigned)__shfl((int)sv, gb + j + 7, 64) + laneoff;
            uint4 u0 = *(const uint4*)(Hb8 + o0);
            uint4 u1 = *(const uint4*)(Hb8 + o1);
            uint4 u2 = *(const uint4*)(Hb8 + o2);
            uint4 u3 = *(const uint4*)(Hb8 + o3);
            uint4 u4 = *(const uint4*)(Hb8 + o4);
            uint4 u5 = *(const uint4*)(Hb8 + o5);
            uint4 u6 = *(const uint4*)(Hb8 + o6);
            uint4 u7 = *(const uint4*)(Hb8 + o7);
            accA[0] += as_h2(u0.x); accA[1] += as_h2(u0.y); accA[2] += as_h2(u0.z); accA[3] += as_h2(u0.w);
            accB[0] += as_h2(u1.x); accB[1] += as_h2(u1.y); accB[2] += as_h2(u1.z); accB[3] += as_h2(u1.w);
            accC[0] += as_h2(u2.x); accC[1] += as_h2(u2.y); accC[2] += as_h2(u2.z); accC[3] += as_h2(u2.w);
            accD[0] += as_h2(u3.x); accD[1] += as_h2(u3.y); accD[2] += as_h2(u3.z); accD[3] += as_h2(u3.w);
            accA[0] += as_h2(u4.x); accA[1] += as_h2(u4.y); accA[2] += as_h2(u4.z); accA[3] += as_h2(u4.w);
            accB[0] += as_h2(u5.x); accB[1] += as_h2(u5.y); accB[2] += as_h2(u5.z); accB[3] += as_h2(u5.w);
            accC[0] += as_h2(u6.x); accC[1] += as_h2(u6.y); accC[2] += as_h2(u6.z); accC[3] += as_h2(u6.w);
            accD[0] += as_h2(u7.x); accD[1] += as_h2(u7.y); accD[2] += as_h2(u7.z); accD[3] += as_h2(u7.w);
        }
    }

#pragma unroll
    for (int k = 0; k < 4; ++k) accA[k] = (accA[k] + accB[k]) + (accC[k] + accD[k]);

    const float dv = dinv[node];
    const unsigned nodeoff = ((unsigned)node << 8) + laneoff;
    uint4 hv = *(const uint4*)(Hb8 + nodeoff);       // h'[node] (pre-scaled)
    const int c0 = l16 * 8;
    float4 bb0 = *(const float4*)(bias + c0);
    float4 bb1 = *(const float4*)(bias + c0 + 4);
    f16x2 h0 = as_h2(hv.x), h1 = as_h2(hv.y), h2 = as_h2(hv.z), h3 = as_h2(hv.w);

    float a[8];
    a[0] = ((float)accA[0].x + (float)h0.x) * dv + bb0.x;
    a[1] = ((float)accA[0].y + (float)h0.y) * dv + bb0.y;
    a[2] = ((float)accA[1].x + (float)h1.x) * dv + bb0.z;
    a[3] = ((float)accA[1].y + (float)h1.y) * dv + bb0.w;
    a[4] = ((float)accA[2].x + (float)h2.x) * dv + bb1.x;
    a[5] = ((float)accA[2].y + (float)h2.y) * dv + bb1.y;
    a[6] = ((float)accA[3].x + (float)h3.x) * dv + bb1.z;
    a[7] = ((float)accA[3].y + (float)h3.y) * dv + bb1.w;

    float s1 = 0.f, s2 = 0.f;
#pragma unroll
    for (int i = 0; i < 8; ++i) { s1 += a[i]; s2 += a[i] * a[i]; }
#pragma unroll
    for (int mk = 1; mk <= 8; mk <<= 1) {
        s1 += __shfl_xor(s1, mk, 64);
        s2 += __shfl_xor(s2, mk, 64);
    }
    float mean = s1 * (1.0f / 128.0f);
    float var  = s2 * (1.0f / 128.0f) - mean * mean;
    float rr   = rsqrtf(var + 1e-5f);

    float4 gg0 = *(const float4*)(g + c0);
    float4 gg1 = *(const float4*)(g + c0 + 4);
    float4 ee0 = *(const float4*)(be + c0);
    float4 ee1 = *(const float4*)(be + c0 + 4);

    float r[8];
    r[0] = (a[0] - mean) * rr * gg0.x + ee0.x;
    r[1] = (a[1] - mean) * rr * gg0.y + ee0.y;
    r[2] = (a[2] - mean) * rr * gg0.z + ee0.z;
    r[3] = (a[3] - mean) * rr * gg0.w + ee0.w;
    r[4] = (a[4] - mean) * rr * gg1.x + ee1.x;
    r[5] = (a[5] - mean) * rr * gg1.y + ee1.y;
    r[6] = (a[6] - mean) * rr * gg1.z + ee1.z;
    r[7] = (a[7] - mean) * rr * gg1.w + ee1.w;
#pragma unroll
    for (int i = 0; i < 8; ++i) r[i] = r[i] > 0.0f ? r[i] : expm1f(r[i]);

    if (xin) {
        uint4 xv = *(const uint4*)((const char*)xin + nodeoff);
        f16x2 x0 = as_h2(xv.x), x1 = as_h2(xv.y), x2 = as_h2(xv.z), x3 = as_h2(xv.w);
        r[0] += (float)x0.x; r[1] += (float)x0.y;
        r[2] += (float)x1.x; r[3] += (float)x1.y;
        r[4] += (float)x2.x; r[5] += (float)x2.y;
        r[6] += (float)x3.x; r[7] += (float)x3.y;
    }

    uint4 o;
    o.x = pack_h2(r[0], r[1]);
    o.y = pack_h2(r[2], r[3]);
    o.z = pack_h2(r[4], r[5]);
    o.w = pack_h2(r[6], r[7]);
    *(uint4*)((char*)Cout + nodeoff) = o;        // residual source for next layer
    *(uint4*)&hl[grp][l16 * 8] = o;              // GEMM A-tile
    __syncthreads();

    // ---- next-layer GEMM: 16x128 tile, 2 col-tiles per wave ----
    {
        const int m = lane & 15;
        const int q = lane >> 4;

        f16x8 af[4];
#pragma unroll
        for (int s = 0; s < 4; ++s)
            af[s] = *(const f16x8*)&hl[m][q * 8 + s * 32];

        f32x4 acc2[2];
        f32x4 z = {0.f, 0.f, 0.f, 0.f};
        acc2[0] = z; acc2[1] = z;

#pragma unroll
        for (int s = 0; s < 4; ++s)
#pragma unroll
            for (int p = 0; p < 2; ++p) {
                f16x8 wfv = *(const f16x8*)(Wsw + (((2 * wave + p) * 4 + s) << 9) + lane * 8);
                acc2[p] = __builtin_amdgcn_mfma_f32_16x16x32_f16(af[s], wfv, acc2[p], 0, 0, 0);
            }

#pragma unroll
        for (int j = 0; j < 4; ++j) {
            int row = node0 + q * 4 + j;
            float dv2 = dinv[row];
            // cols m*8 + 2*wave, m*8 + 2*wave + 1 (contiguous pair)
            *(unsigned*)((char*)Hout + ((unsigned)row << 8) + ((unsigned)(m * 8 + 2 * wave) << 1)) =
                pack_h2(acc2[0][j] * dv2, acc2[1][j] * dv2);
        }
    }
}

// ---------------------------------------------------------------- layer-2 agg + LN + ELU + residual + CLASSIFIER (fused)
__global__ __launch_bounds__(256) void agg_ln_cls(const unsigned short* __restrict__ Hh,
                                                  const unsigned short* __restrict__ xin,
                                                  const float* __restrict__ dinv,
                                                  const float* __restrict__ bias,
                                                  const float* __restrict__ g,
                                                  const float* __restrict__ be,
                                                  const int* __restrict__ rowptr,
                                                  const unsigned* __restrict__ rec,
                                                  const unsigned short* __restrict__ Wcsw,
                                                  const float* __restrict__ bc,
                                                  float* __restrict__ out) {
    __shared__ _Float16 hl[16][136];
    const int tid  = threadIdx.x;
    const int lane = tid & 63;
    const int l16  = tid & 15;
    const int gb   = lane & 48;
    const int grp  = tid >> 4;
    const int node0 = blockIdx.x * 16;
    const int node = node0 + grp;
    const int beg  = rowptr[node];
    const int end  = rowptr[node + 1];
    const char* Hb8 = (const char*)Hh;
    const unsigned laneoff = (unsigned)l16 * 16;
    const unsigned sentin  = (unsigned)N_NODES << 8;

    f16x2 accA[4], accB[4], accC[4], accD[4];
    f16x2 hz = {(_Float16)0.f, (_Float16)0.f};
#pragma unroll
    for (int k = 0; k < 4; ++k) { accA[k] = hz; accB[k] = hz; accC[k] = hz; accD[k] = hz; }

    for (int e0 = beg; e0 < end; e0 += 16) {
        int cnt = min(end - e0, 16);
        unsigned sv = (l16 < cnt) ? rec[e0 + l16] : sentin;
        int cntR = (cnt + 7) & ~7;
        for (int j = 0; j < cntR; j += 8) {
            unsigned o0 = (unsigned)__shfl((int)sv, gb + j + 0, 64) + laneoff;
            unsigned o1 = (unsigned)__shfl((int)sv, gb + j + 1, 64) + laneoff;
            unsigned o2 = (unsigned)__shfl((int)sv, gb + j + 2, 64) + laneoff;
            unsigned o3 = (unsigned)__shfl((int)sv, gb + j + 3, 64) + laneoff;
            unsigned o4 = (unsigned)__shfl((int)sv, gb + j + 4, 64) + laneoff;
            unsigned o5 = (unsigned)__shfl((int)sv, gb + j + 5, 64) + laneoff;
            unsigned o6 = (unsigned)__shfl((int)sv, gb + j + 6, 64) + laneoff;
            unsigned o7 = (unsigned)__shfl((int)sv, gb + j + 7, 64) + laneoff;
            uint4 u0 = *(const uint4*)(Hb8 + o0);
            uint4 u1 = *(const uint4*)(Hb8 + o1);
            uint4 u2 = *(const uint4*)(Hb8 + o2);
            uint4 u3 = *(const uint4*)(Hb8 + o3);
            uint4 u4 = *(const uint4*)(Hb8 + o4);
            uint4 u5 = *(const uint4*)(Hb8 + o5);
            uint4 u6 = *(const uint4*)(Hb8 + o6);
            uint4 u7 = *(const uint4*)(Hb8 + o7);
            accA[0] += as_h2(u0.x); accA[1] += as_h2(u0.y); accA[2] += as_h2(u0.z); accA[3] += as_h2(u0.w);
            accB[0] += as_h2(u1.x); accB[1] += as_h2(u1.y); accB[2] += as_h2(u1.z); accB[3] += as_h2(u1.w);
            accC[0] += as_h2(u2.x); accC[1] += as_h2(u2.y); accC[2] += as_h2(u2.z); accC[3] += as_h2(u2.w);
            accD[0] += as_h2(u3.x); accD[1] += as_h2(u3.y); accD[2] += as_h2(u3.z); accD[3] += as_h2(u3.w);
            accA[0] += as_h2(u4.x); accA[1] += as_h2(u4.y); accA[2] += as_h2(u4.z); accA[3] += as_h2(u4.w);
            accB[0] += as_h2(u5.x); accB[1] += as_h2(u5.y); accB[2] += as_h2(u5.z); accB[3] += as_h2(u5.w);
            accC[0] += as_h2(u6.x); accC[1] += as_h2(u6.y); accC[2] += as_h2(u6.z); accC[3] += as_h2(u6.w);
            accD[0] += as_h2(u7.x); accD[1] += as_h2(u7.y); accD[2] += as_h2(u7.z); accD[3] += as_h2(u7.w);
        }
    }

#pragma unroll
    for (int k = 0; k < 4; ++k) accA[k] = (accA[k] + accB[k]) + (accC[k] + accD[k]);

    const float dv = dinv[node];
    const unsigned nodeoff = ((unsigned)node << 8) + laneoff;
    uint4 hv = *(const uint4*)(Hb8 + nodeoff);
    const int c0 = l16 * 8;
    float4 bb0 = *(const float4*)(bias + c0);
    float4 bb1 = *(const float4*)(bias + c0 + 4);
    f16x2 h0 = as_h2(hv.x), h1 = as_h2(hv.y), h2 = as_h2(hv.z), h3 = as_h2(hv.w);

    float a[8];
    a[0] = ((float)accA[0].x + (float)h0.x) * dv + bb0.x;
    a[1] = ((float)accA[0].y + (float)h0.y) * dv + bb0.y;
    a[2] = ((float)accA[1].x + (float)h1.x) * dv + bb0.z;
    a[3] = ((float)accA[1].y + (float)h1.y) * dv + bb0.w;
    a[4] = ((float)accA[2].x + (float)h2.x) * dv + bb1.x;
    a[5] = ((float)accA[2].y + (float)h2.y) * dv + bb1.y;
    a[6] = ((float)accA[3].x + (float)h3.x) * dv + bb1.z;
    a[7] = ((float)accA[3].y + (float)h3.y) * dv + bb1.w;

    float s1 = 0.f, s2 = 0.f;
#pragma unroll
    for (int i = 0; i < 8; ++i) { s1 += a[i]; s2 += a[i] * a[i]; }
#pragma unroll
    for (int mk = 1; mk <= 8; mk <<= 1) {
        s1 += __shfl_xor(s1, mk, 64);
        s2 += __shfl_xor(s2, mk, 64);
    }
    float mean = s1 * (1.0f / 128.0f);
    float var  = s2 * (1.0f / 128.0f) - mean * mean;
    float rr   = rsqrtf(var + 1e-5f);

    float4 gg0 = *(const float4*)(g + c0);
    float4 gg1 = *(const float4*)(g + c0 + 4);
    float4 ee0 = *(const float4*)(be + c0);
    float4 ee1 = *(const float4*)(be + c0 + 4);

    float r[8];
    r[0] = (a[0] - mean) * rr * gg0.x + ee0.x;
    r[1] = (a[1] - mean) * rr * gg0.y + ee0.y;
    r[2] = (a[2] - mean) * rr * gg0.z + ee0.z;
    r[3] = (a[3] - mean) * rr * gg0.w + ee0.w;
    r[4] = (a[4] - mean) * rr * gg1.x + ee1.x;
    r[5] = (a[5] - mean) * rr * gg1.y + ee1.y;
    r[6] = (a[6] - mean) * rr * gg1.z + ee1.z;
    r[7] = (a[7] - mean) * rr * gg1.w + ee1.w;
#pragma unroll
    for (int i = 0; i < 8; ++i) r[i] = r[i] > 0.0f ? r[i] : expm1f(r[i]);

    if (xin) {
        uint4 xv = *(const uint4*)((const char*)xin + nodeoff);
        f16x2 x0 = as_h2(xv.x), x1 = as_h2(xv.y), x2 = as_h2(xv.z), x3 = as_h2(xv.w);
        r[0] += (float)x0.x; r[1] += (float)x0.y;
        r[2] += (float)x1.x; r[3] += (float)x1.y;
        r[4] += (float)x2.x; r[5] += (float)x2.y;
        r[6] += (float)x3.x; r[7] += (float)x3.y;
    }

    uint4 o;
    o.x = pack_h2(r[0], r[1]);
    o.y = pack_h2(r[2], r[3]);
    o.z = pack_h2(r[4], r[5]);
    o.w = pack_h2(r[6], r[7]);
    *(uint4*)&hl[grp][l16 * 8] = o;
    __syncthreads();

    if (tid < 64) {
        const int m = lane & 15;
        const int q = lane >> 4;

        f16x8 wf[12];
#pragma unroll
        for (int f = 0; f < 12; ++f)
            wf[f] = *(const f16x8*)(Wcsw + (f << 9) + lane * 8);

        f16x8 af[4];
#pragma unroll
        for (int s = 0; s < 4; ++s)
            af[s] = *(const f16x8*)&hl[m][q * 8 + s * 32];

        f32x4 acc[3];
        f32x4 z = {0.f, 0.f, 0.f, 0.f};
#pragma unroll
        for (int n = 0; n < 3; ++n) acc[n] = z;

#pragma unroll
        for (int s = 0; s < 4; ++s)
#pragma unroll
            for (int n = 0; n < 3; ++n)
                acc[n] = __builtin_amdgcn_mfma_f32_16x16x32_f16(af[s], wf[n * 4 + s], acc[n], 0, 0, 0);

#pragma unroll
        for (int j = 0; j < 4; ++j) {
            int row = node0 + q * 4 + j;
#pragma unroll
            for (int n = 0; n < 3; ++n) {
                int c = 3 * m + n;
                if (c < NCLS)
                    out[(size_t)row * NCLS + c] = acc[n][j] + bc[c];
            }
        }
    }
}

// ---------------------------------------------------------------- launch
extern "C" void kernel_launch(void* const* d_in, const int* in_sizes, int n_in,
                              void* d_out, int out_size, void* d_ws, size_t ws_size,
                              hipStream_t stream) {
    const float* x  = (const float*)d_in[0];
    const int*   ei = (const int*)d_in[1];
    const float* W[3]  = {(const float*)d_in[2], (const float*)d_in[6], (const float*)d_in[10]};
    const float* b[3]  = {(const float*)d_in[3], (const float*)d_in[7], (const float*)d_in[11]};
    const float* g[3]  = {(const float*)d_in[4], (const float*)d_in[8], (const float*)d_in[12]};
    const float* be[3] = {(const float*)d_in[5], (const float*)d_in[9], (const float*)d_in[13]};
    const float* Wc = (const float*)d_in[14];
    const float* bc = (const float*)d_in[15];
    float* out = (float*)d_out;

    char* ws = (char*)d_ws;
    const size_t NP = 400128;  // padded (N+1)*4 bytes
    float* dinv   = (float*)(ws);
    int*   rowptr = (int*)  (ws + NP);
    int*   bcnt   = (int*)  (ws + 2 * NP);
    int*   boff   = (int*)  (ws + 2 * NP + 1024);
    unsigned* rec = (unsigned*)(ws + 2 * NP + 4096);
    unsigned short* H1 = (unsigned short*)(ws + 2 * NP + 4096 + (size_t)N_EDGES * 8);
    unsigned short* H2 = H1 + (size_t)(N_NODES + 64) * DIM;   // both H buffers have zero-pad rows
    unsigned short* Ch = H2 + (size_t)(N_NODES + 64) * DIM;
    unsigned short* Wsw0 = Ch + (size_t)N_NODES * DIM;
    unsigned short* Wsw1 = Wsw0 + DIM * DIM;
    unsigned short* Wsw2 = Wsw1 + DIM * DIM;
    unsigned short* Wcsw = Wsw2 + DIM * DIM;   // 12*512 shorts
    unsigned* tmp = (unsigned*)Ch;             // aliases Ch; dead before agg0 writes Ch

    // ---- setup: zero bcnt+boff (memset) + swizzles + histogram + H2-pad zero ----
    hipMemsetAsync(bcnt, 0, 2048, stream);
    setup_misc<<<216 + P1_GRID + 1, 256, 0, stream>>>(W[0], W[1], W[2], Wc, ei,
                                                      Wsw0, Wsw1, Wsw2, Wcsw, bcnt, H2);

    // ---- CSR build ----
    bucket_p1<<<P1_GRID, 256, 0, stream>>>(ei, bcnt, boff, tmp);
    bucket_p2<<<NBUCK, 256, 0, stream>>>(tmp, bcnt, rowptr, dinv, rec);

    const int gemm_grid = (N_NODES + 63) / 64;    // 1563 (covers pad rows to 100032)
    const int agg_grid  = N_NODES / 16;           // 6250 (16 nodes/block, quarter-wave each)

    // layer 0 GEMM: x fp32 -> H1 (scaled)
    gemm_mfma_f<<<gemm_grid, 256, 0, stream>>>(x, Wsw0, dinv, H1);

    // layer 0 agg + layer 1 GEMM: gather H1 -> Ch (residual), GEMM -> H2
    agg_ln_gemm<<<agg_grid, 256, 0, stream>>>(H1, nullptr, dinv, b[0], g[0], be[0],
                                              rowptr, rec, Wsw1, Ch, H2);

    // layer 1 agg + layer 2 GEMM: gather H2, resid Ch -> Ch (in-place), GEMM -> H1
    agg_ln_gemm<<<agg_grid, 256, 0, stream>>>(H2, Ch, dinv, b[1], g[1], be[1],
                                              rowptr, rec, Wsw2, Ch, H1);

    // layer 2 agg + classifier: gather H1, resid Ch -> logits
    agg_ln_cls<<<agg_grid, 256, 0, stream>>>(H1, Ch, dinv, b[2], g[2], be[2],
                                             rowptr, rec, Wcsw, bc, out);
}